// Round 13
// baseline (300.576 us; speedup 1.0000x reference)
//
#include <hip/hip_runtime.h>
#include <hip/hip_cooperative_groups.h>
#include <hip/hip_bf16.h>
#include <math.h>

namespace cg = cooperative_groups;

#define H 768
#define BM 128

typedef __attribute__((ext_vector_type(4))) float f32x4;
typedef __attribute__((ext_vector_type(8))) short bf16x8;

__device__ __forceinline__ float bf2f(unsigned u16v){
  return __uint_as_float((u16v & 0xffffu) << 16);
}
__device__ __forceinline__ unsigned f2bf2(float a, float b){
  __hip_bfloat16 ha = __float2bfloat16(a), hb = __float2bfloat16(b);
  return (unsigned)*(unsigned short*)&ha | ((unsigned)*(unsigned short*)&hb << 16);
}
__device__ __forceinline__ float gelu_exact(float x){
  return 0.5f * x * (1.0f + erff(x * 0.70710678118654752f));
}
__device__ __forceinline__ void gload16(const void* g, void* l){
  __builtin_amdgcn_global_load_lds(
      (const __attribute__((address_space(1))) unsigned int*)g,
      (__attribute__((address_space(3))) unsigned int*)l,
      16, 0, 0);
}
__device__ __forceinline__ float wave_sum(float p){
#pragma unroll
  for (int o = 32; o; o >>= 1) p += __shfl_xor(p, o);
  return p;
}
__device__ __forceinline__ int e_src(const int* ep, int E0, int k){
  return (k < E0) ? ep[k] : (k - E0);
}
__device__ __forceinline__ int e_dst(const int* ep, int E0, int k){
  return (k < E0) ? ep[E0 + k] : (k - E0);
}

// ---------------- cooperative preprocessing megakernel ----------------
// Phases (grid.sync between each): zero cnt/flag/flag2 -> count+S3-mark ->
// S2-mark -> tri chunk-scan -> sums wave-scan -> apply offsets + emit lists
// + init cur -> fill CSR (S3-dst edges only). Bodies identical to the
// round-12 validated kernels; only the sync mechanism changed.
__global__ __launch_bounds__(1024) void preproc_kernel(
    const int* __restrict__ ep, int E0, int E, int N, int L,
    int* cnt, int* flag, int* flag2, int* off, int* cur, int* csr,
    int* sums, int* fpos, int* fsums, int* fpos2, int* fsums2,
    int* list, int* list2){
  cg::grid_group grid = cg::this_grid();
  __shared__ int lds[1024];
  const int tid = threadIdx.x;
  const int gid = blockIdx.x * blockDim.x + tid;
  const int gsz = gridDim.x * blockDim.x;
  const int nchunk = (N + 1023) >> 10;          // 49 (<= 64, <= gridDim.x)

  // phase 0: zero cnt/flag/flag2 (contiguous 3N ints)
  for (int i = gid; i < 3 * N; i += gsz) cnt[i] = 0;
  grid.sync();
  // phase 1: edge count by dst + S3 marking (srcs of dst<L edges)
  for (int k = gid; k < E; k += gsz){
    int d = e_dst(ep, E0, k);
    atomicAdd(&cnt[d], 1);
    if (d < L) flag[e_src(ep, E0, k)] = 1;      // benign same-value race
  }
  grid.sync();
  // phase 2: S2 marking (srcs of edges whose dst is in S3)
  for (int k = gid; k < E; k += gsz)
    if (flag[e_dst(ep, E0, k)]) flag2[e_src(ep, E0, k)] = 1;
  grid.sync();
  // phase 3: tri chunk-scan (blocks 0..nchunk-1, 1024 elems each)
  {
    const int* as[3] = {cnt, flag, flag2};
    int* os[3] = {off, fpos, fpos2};
    int* ss[3] = {sums, fsums, fsums2};
    if ((int)blockIdx.x < nchunk){
      int gi = blockIdx.x * 1024 + tid;
      for (int q = 0; q < 3; q++){
        __syncthreads();
        int v = (gi < N) ? as[q][gi] : 0;
        lds[tid] = v;
        __syncthreads();
        for (int o = 1; o < 1024; o <<= 1){
          int tv = (tid >= o) ? lds[tid - o] : 0;
          __syncthreads();
          lds[tid] += tv;
          __syncthreads();
        }
        if (gi < N) os[q][gi] = lds[tid] - v;   // exclusive within chunk
        if (tid == 1023) ss[q][blockIdx.x] = lds[1023];
      }
    }
  }
  grid.sync();
  // phase 4: wave-scan of the three sums arrays (block 0, wave 0)
  if (blockIdx.x == 0 && tid < 64){
    int* ss[3] = {sums, fsums, fsums2};
    int* os[3] = {off, fpos, fpos2};
    for (int q = 0; q < 3; q++){
      int v = (tid < nchunk) ? ss[q][tid] : 0;
      int incl = v;
#pragma unroll
      for (int o = 1; o < 64; o <<= 1){
        int t2 = __shfl_up(incl, o);
        if (tid >= o) incl += t2;
      }
      if (tid < nchunk) ss[q][tid] = incl - v;  // exclusive block offsets
      if (tid == nchunk - 1) os[q][N] = incl;   // totals: E, |S3|, |S2|
    }
  }
  grid.sync();
  // phase 5: apply block offsets; init cur; emit ordered S3/S2 lists
  if ((int)blockIdx.x < nchunk){
    int gi = blockIdx.x * 1024 + tid;
    if (gi < N){
      int v = off[gi] + sums[blockIdx.x];
      off[gi] = v;
      cur[gi] = v;
      int fp = fpos[gi] + fsums[blockIdx.x];
      if (flag[gi]) list[fp] = gi;
      int fp2 = fpos2[gi] + fsums2[blockIdx.x];
      if (flag2[gi]) list2[fp2] = gi;
    }
  }
  grid.sync();
  // phase 6: fill CSR — only edges whose dst is aggregated (dst in S3)
  for (int k = gid; k < E; k += gsz){
    int d = e_dst(ep, E0, k);
    if (flag[d]) csr[atomicAdd(&cur[d], 1)] = k;
  }
}

// ---------------- LayerNorm + exact GELU over a row LIST (grid-stride) ----------------
__global__ __launch_bounds__(256) void lnw_list_kernel(
    const float* __restrict__ in, const float* __restrict__ g,
    const float* __restrict__ b, __hip_bfloat16* __restrict__ out,
    const int* __restrict__ rlist, const int* __restrict__ np){
  int lim = *np;
  int lane = threadIdx.x & 63;
  for (int i = blockIdx.x * 4 + (threadIdx.x >> 6); i < lim; i += gridDim.x * 4){
    int row = rlist[i];
    const float* rp = in + (size_t)row * H;
    float v[12];
#pragma unroll
    for (int q = 0; q < 3; q++){
      float4 t = *(const float4*)&rp[(lane + q * 64) * 4];
      v[q*4+0] = t.x; v[q*4+1] = t.y; v[q*4+2] = t.z; v[q*4+3] = t.w;
    }
    float s = 0.f;
#pragma unroll
    for (int t = 0; t < 12; t++) s += v[t];
    float mean = wave_sum(s) * (1.0f / H);
    float s2 = 0.f;
#pragma unroll
    for (int t = 0; t < 12; t++){ float d = v[t] - mean; s2 += d * d; }
    float rstd = rsqrtf(wave_sum(s2) * (1.0f / H) + 1e-5f);
    unsigned* op = (unsigned*)(out + (size_t)row * H);
#pragma unroll
    for (int q = 0; q < 3; q++){
      float4 gv = *(const float4*)&g[(lane + q * 64) * 4];
      float4 bv = *(const float4*)&b[(lane + q * 64) * 4];
      float z0 = gelu_exact((v[q*4+0] - mean) * rstd * gv.x + bv.x);
      float z1 = gelu_exact((v[q*4+1] - mean) * rstd * gv.y + bv.y);
      float z2 = gelu_exact((v[q*4+2] - mean) * rstd * gv.z + bv.z);
      float z3 = gelu_exact((v[q*4+3] - mean) * rstd * gv.w + bv.w);
      uint2 pk; pk.x = f2bf2(z0, z1); pk.y = f2bf2(z2, z3);
      *(uint2*)&op[lane * 2 + q * 128] = pk;
    }
  }
}

// ---------------- weight transpose + f32->bf16 (all 4 matrices, z-indexed) ----------------
__global__ __launch_bounds__(256) void wt_bf16_kernel(
    const float* __restrict__ W0, const float* __restrict__ W1,
    const float* __restrict__ W2, const float* __restrict__ W3,
    __hip_bfloat16* __restrict__ T0, __hip_bfloat16* __restrict__ T1,
    __hip_bfloat16* __restrict__ T2, __hip_bfloat16* __restrict__ T3){
  int z = blockIdx.z;
  const float* W = (z == 0) ? W0 : (z == 1) ? W1 : (z == 2) ? W2 : W3;
  __hip_bfloat16* WT = (z == 0) ? T0 : (z == 1) ? T1 : (z == 2) ? T2 : T3;
  __shared__ float tile[32][33];
  int k0 = blockIdx.x * 32, n0 = blockIdx.y * 32;
  int tx = threadIdx.x & 31, ty = threadIdx.x >> 5;   // 32 x 8
#pragma unroll
  for (int i = 0; i < 32; i += 8)
    tile[ty + i][tx] = W[(size_t)(k0 + ty + i) * H + n0 + tx];
  __syncthreads();
#pragma unroll
  for (int i = 0; i < 32; i += 8)
    WT[(size_t)(n0 + ty + i) * H + k0 + tx] = __float2bfloat16(tile[tx][ty + i]);
}

// ---------------- 128x128 4-wave GEMM, dual row-compaction (both layers) ----------------
__global__ __launch_bounds__(256, 3) void gemm_fused_kernel(
    const __hip_bfloat16* __restrict__ A,
    const __hip_bfloat16* __restrict__ WT,
    const float* __restrict__ bl, const float* __restrict__ br,
    __hip_bfloat16* __restrict__ Cl, __hip_bfloat16* __restrict__ Cr,
    const int* __restrict__ rmapL, const int* __restrict__ nrLp,
    const int* __restrict__ rmapR, const int* __restrict__ nrRp, int MrR){
  __shared__ char smem[49152];          // 3 x (As 8KB | Bs 8KB)

  int wgid = blockIdx.x;
  int panel = wgid / 12, colblk = wgid % 12;   // identity: spreads active blocks
  int row0 = panel * BM;
  const bool is_r = colblk >= 6;
  const int* rmap = is_r ? rmapR : rmapL;
  int nr = is_r ? (rmapR ? *nrRp : MrR) : *nrLp;
  if (row0 >= nr) return;
  const bool remap = (rmap != nullptr);

  const int t = threadIdx.x;
  const int sr = t >> 2;
  const int scs = (((t & 3) ^ ((sr >> 1) & 3)) * 8);
  const int t16 = t * 16;
  int ra0 = min(row0 + sr, nr - 1), ra1 = min(row0 + sr + 64, nr - 1);
  if (remap){ ra0 = rmap[ra0]; ra1 = rmap[ra1]; }
  const __hip_bfloat16* pa0 = A + (size_t)ra0 * H + scs;
  const __hip_bfloat16* pa1 = A + (size_t)ra1 * H + scs;
  const __hip_bfloat16* pb0 = WT + (size_t)(colblk * 128 + sr) * H + scs;
  const __hip_bfloat16* pb1 = pb0 + (size_t)64 * H;

  const int l = t & 63, w = t >> 6;
  const int wm = (w >> 1) * 64, wn = (w & 1) * 64;
  const int r0 = l & 15;
  const int kcs2 = (((l >> 4) ^ ((r0 >> 1) & 3)) * 16);

  f32x4 acc[4][4];
#pragma unroll
  for (int m = 0; m < 4; m++)
#pragma unroll
    for (int n = 0; n < 4; n++) acc[m][n] = (f32x4){0.f, 0.f, 0.f, 0.f};

#define STAGE(kt, b) do{                                   \
    int _k0 = (kt) * 32;                                   \
    char* _bs = smem + (b) * 16384;                        \
    gload16(pa0 + _k0, _bs + t16);                         \
    gload16(pa1 + _k0, _bs + 4096 + t16);                  \
    gload16(pb0 + _k0, _bs + 8192 + t16);                  \
    gload16(pb1 + _k0, _bs + 12288 + t16);                 \
  }while(0)

  STAGE(0, 0);
  STAGE(1, 1);

  for (int kt = 0; kt < 24; kt++){
    if (kt < 23) asm volatile("s_waitcnt vmcnt(4)" ::: "memory");
    else         asm volatile("s_waitcnt vmcnt(0)" ::: "memory");
    __builtin_amdgcn_s_barrier();
    __builtin_amdgcn_sched_barrier(0);
    if (kt + 2 < 24) STAGE(kt + 2, (kt + 2) % 3);
    const char* base = smem + (kt % 3) * 16384;
    bf16x8 af[4], bfr[4];
#pragma unroll
    for (int m = 0; m < 4; m++)
      af[m]  = *(const bf16x8*)(base + (wm + m * 16 + r0) * 64 + kcs2);
#pragma unroll
    for (int n = 0; n < 4; n++)
      bfr[n] = *(const bf16x8*)(base + 8192 + (wn + n * 16 + r0) * 64 + kcs2);
#pragma unroll
    for (int m = 0; m < 4; m++)
#pragma unroll
      for (int n = 0; n < 4; n++)
        acc[m][n] = __builtin_amdgcn_mfma_f32_16x16x32_bf16(af[m], bfr[n], acc[m][n], 0, 0, 0);
  }
#undef STAGE

  __syncthreads();
  const int rgrp = (l >> 4) * 4;
  const float* bp = is_r ? br : bl;
  const int cb = (is_r ? colblk - 6 : colblk) * 128;
#pragma unroll
  for (int n = 0; n < 4; n++){
    int lc = wn + n * 16 + r0;
    float bb = bp[cb + lc];
#pragma unroll
    for (int m = 0; m < 4; m++){
#pragma unroll
      for (int jj = 0; jj < 4; jj++){
        int lr = wm + m * 16 + rgrp + jj;
        int byte = lr * 256 + ((lc * 2) ^ (((lr >> 2) & 3) << 5));
        *(__hip_bfloat16*)(smem + byte) = __float2bfloat16(acc[m][n][jj] + bb);
      }
    }
  }
  __syncthreads();
  __hip_bfloat16* C = is_r ? Cr : Cl;
#pragma unroll
  for (int p = 0; p < 8; p++){
    int ba = p * 4096 + t16;
    int lr = ba >> 8, inner = ba & 255;
    int gr = row0 + lr;
    if (gr >= nr) continue;
    int orow = remap ? rmap[gr] : gr;
    uint4 v = *(const uint4*)(smem + lr * 256 + (inner ^ (((lr >> 2) & 3) << 5)));
    *(uint4*)(C + (size_t)orow * H + cb + (inner >> 1)) = v;
  }
}

// ---------------- fused GAT attend+aggregate+LN+GELU: one WAVE per dst (grid-stride) ----------------
template<typename OutT>
__global__ __launch_bounds__(256) void agat_kernel(
    const __hip_bfloat16* __restrict__ xl, const __hip_bfloat16* __restrict__ xr,
    const float* __restrict__ att, const int* __restrict__ off,
    const int* __restrict__ csr, const int* __restrict__ ep, int E0,
    const float* __restrict__ bias, const float* __restrict__ g,
    const float* __restrict__ b, OutT* __restrict__ out,
    const int* __restrict__ dlist, const int* __restrict__ ndp, int ndst){
  int lim = dlist ? *ndp : ndst;
  int lane = threadIdx.x & 63;
  for (int i = blockIdx.x * 4 + (threadIdx.x >> 6); i < lim; i += gridDim.x * 4){
    int d = dlist ? dlist[i] : i;
    float xrv[12], attv[12];
    const unsigned* pr = (const unsigned*)(xr + (size_t)d * H);
#pragma unroll
    for (int q = 0; q < 3; q++){
      uint2 vr = *(const uint2*)&pr[lane * 2 + q * 128];
      float4 av = *(const float4*)&att[(lane + q * 64) * 4];
      xrv[q*4+0] = bf2f(vr.x); xrv[q*4+1] = bf2f(vr.x >> 16);
      xrv[q*4+2] = bf2f(vr.y); xrv[q*4+3] = bf2f(vr.y >> 16);
      attv[q*4+0] = av.x; attv[q*4+1] = av.y; attv[q*4+2] = av.z; attv[q*4+3] = av.w;
    }
    float m = -INFINITY, den = 0.f, acc[12];
#pragma unroll
    for (int t = 0; t < 12; t++) acc[t] = 0.f;
    int j0 = off[d], j1 = off[d + 1];
    int sj = (j0 < j1) ? e_src(ep, E0, csr[j0]) : 0;   // src prefetch pipeline
    for (int j = j0; j < j1; j++){
      int s_ = sj;
      if (j + 1 < j1) sj = e_src(ep, E0, csr[j + 1]);
      const unsigned* pl = (const unsigned*)(xl + (size_t)s_ * H);
      float xv[12];
#pragma unroll
      for (int q = 0; q < 3; q++){
        uint2 vl = *(const uint2*)&pl[lane * 2 + q * 128];
        xv[q*4+0] = bf2f(vl.x); xv[q*4+1] = bf2f(vl.x >> 16);
        xv[q*4+2] = bf2f(vl.y); xv[q*4+3] = bf2f(vl.y >> 16);
      }
      float p = 0.f;
#pragma unroll
      for (int t = 0; t < 12; t++){
        float v = xv[t] + xrv[t];
        v = (v > 0.f) ? v : 0.2f * v;
        p += v * attv[t];
      }
      p = wave_sum(p);
      float mn = fmaxf(m, p);
      float sc = __expf(m - mn), wgt = __expf(p - mn);
      den = den * sc + wgt;
#pragma unroll
      for (int t = 0; t < 12; t++) acc[t] = acc[t] * sc + wgt * xv[t];
      m = mn;
    }
    float inv = 1.0f / den;
    float y[12];
    float s1 = 0.f;
#pragma unroll
    for (int q = 0; q < 3; q++){
      float4 bv = *(const float4*)&bias[(lane + q * 64) * 4];
      y[q*4+0] = acc[q*4+0] * inv + bv.x;
      y[q*4+1] = acc[q*4+1] * inv + bv.y;
      y[q*4+2] = acc[q*4+2] * inv + bv.z;
      y[q*4+3] = acc[q*4+3] * inv + bv.w;
    }
#pragma unroll
    for (int t = 0; t < 12; t++) s1 += y[t];
    float mean = wave_sum(s1) * (1.0f / H);
    float s2 = 0.f;
#pragma unroll
    for (int t = 0; t < 12; t++){ float dt = y[t] - mean; s2 += dt * dt; }
    float rstd = rsqrtf(wave_sum(s2) * (1.0f / H) + 1e-5f);
    OutT* op = out + (size_t)d * H;
#pragma unroll
    for (int q = 0; q < 3; q++){
      float4 gv = *(const float4*)&g[(lane + q * 64) * 4];
      float4 bv = *(const float4*)&b[(lane + q * 64) * 4];
      float z0 = gelu_exact((y[q*4+0] - mean) * rstd * gv.x + bv.x);
      float z1 = gelu_exact((y[q*4+1] - mean) * rstd * gv.y + bv.y);
      float z2 = gelu_exact((y[q*4+2] - mean) * rstd * gv.z + bv.z);
      float z3 = gelu_exact((y[q*4+3] - mean) * rstd * gv.w + bv.w);
      if constexpr (sizeof(OutT) == 2){
        uint2 pk; pk.x = f2bf2(z0, z1); pk.y = f2bf2(z2, z3);
        *(uint2*)((unsigned*)op + lane * 2 + q * 128) = pk;
      } else {
        float4 fv; fv.x = z0; fv.y = z1; fv.z = z2; fv.w = z3;
        *(float4*)&op[(lane + q * 64) * 4] = fv;
      }
    }
  }
}

extern "C" void kernel_launch(void* const* d_in, const int* in_sizes, int n_in,
                              void* d_out, int out_size, void* d_ws, size_t ws_size,
                              hipStream_t stream){
  const float* emb   = (const float*)d_in[0];
  const float* feats = (const float*)d_in[1];
  const int*   edges = (const int*)d_in[2];
  const float* Wl2 = (const float*)d_in[4],  *bl2 = (const float*)d_in[5];
  const float* Wr2 = (const float*)d_in[6],  *br2 = (const float*)d_in[7];
  const float* att2= (const float*)d_in[8],  *bias2=(const float*)d_in[9];
  const float* Wl3 = (const float*)d_in[10], *bl3 = (const float*)d_in[11];
  const float* Wr3 = (const float*)d_in[12], *br3 = (const float*)d_in[13];
  const float* att3= (const float*)d_in[14], *bias3=(const float*)d_in[15];
  const float* g1 = (const float*)d_in[16], *b1 = (const float*)d_in[17];
  const float* g2 = (const float*)d_in[18], *b2 = (const float*)d_in[19];
  const float* g3 = (const float*)d_in[20], *b3 = (const float*)d_in[21];

  const int N  = in_sizes[1] / H;             // 50000
  const int E0 = in_sizes[2] / 2;             // 100000
  const int E  = E0 + N;                      // 150000
  const int L  = 4096;                        // labels_size
  const int Mpad = ((N + 127) / 128) * 128;            // 50048 rows capacity
  const int panels128 = Mpad / BM;                     // 391

  __hip_bfloat16* ab  = (__hip_bfloat16*)d_ws;          // [Mpad][H] GEMM input
  __hip_bfloat16* xl  = ab + (size_t)Mpad * H;          // [Mpad][H]
  __hip_bfloat16* xr  = xl + (size_t)Mpad * H;          // [Mpad][H]
  __hip_bfloat16* wt2 = xr + (size_t)Mpad * H;          // [1536][H]
  __hip_bfloat16* wt3 = wt2 + (size_t)2 * H * H;        // [1536][H]
  int* cnt   = (int*)(wt3 + (size_t)2 * H * H);         // [N]   (zeroed in-kernel)
  int* flag  = cnt + N;                                 // [N]   S3 flags
  int* flag2 = flag + N;                                // [N]   S2 flags
  int* off   = flag2 + N;                               // [N+1]
  int* cur   = off + N + 1;                             // [N]
  int* csr   = cur + N;                                 // [E]
  int* sums  = csr + E;                                 // [64]
  int* fpos  = sums + 64;                               // [N+1] S3 scan (+count)
  int* fsums = fpos + N + 1;                            // [64]
  int* fpos2 = fsums + 64;                              // [N+1] S2 scan (+count)
  int* fsums2= fpos2 + N + 1;                           // [64]
  int* list  = fsums2 + 64;                             // [N]   S3 row list
  int* list2 = list + N;                                // [N]   S2 row list

  float* out_f = (float*)d_out;

  // output 0: passthrough copy of input_embeddings
  hipMemcpyAsync(out_f, emb, (size_t)in_sizes[0] * sizeof(float),
                 hipMemcpyDeviceToDevice, stream);

  // cooperative preprocessing: CSR + S3/S2 backward-slice lists in ONE kernel
  {
    const int* ep = edges;
    int e0 = E0, e = E, n = N, lv = L;
    void* args[] = {(void*)&ep, (void*)&e0, (void*)&e, (void*)&n, (void*)&lv,
                    (void*)&cnt, (void*)&flag, (void*)&flag2, (void*)&off,
                    (void*)&cur, (void*)&csr, (void*)&sums, (void*)&fpos,
                    (void*)&fsums, (void*)&fpos2, (void*)&fsums2,
                    (void*)&list, (void*)&list2};
    hipLaunchCooperativeKernel((void*)preproc_kernel, dim3(128), dim3(1024),
                               args, 0, stream);
  }

  // weights -> bf16 transposed, concatenated [Wl^T ; Wr^T] (one launch)
  dim3 wgrid(H / 32, H / 32, 4);
  wt_bf16_kernel<<<wgrid, 256, 0, stream>>>(Wl2, Wr2, Wl3, Wr3,
                                            wt2, wt2 + (size_t)H * H,
                                            wt3, wt3 + (size_t)H * H);

  const int* nS3 = fpos + N;    // |S3|
  const int* nS2 = fpos2 + N;   // |S2|

  // ---- layer 1 (sliced): LN over S2; xl over S2, xr over S3; aggregate dst in S3 ----
  lnw_list_kernel<<<2048, 256, 0, stream>>>(feats, g1, b1, ab, list2, nS2);
  gemm_fused_kernel<<<panels128 * 12, 256, 0, stream>>>(ab, wt2, bl2, br2, xl, xr,
                                                        list2, nS2, list, nS3, 0);
  agat_kernel<__hip_bfloat16><<<2048, 256, 0, stream>>>(
      xl, xr, att2, off, csr, edges, E0, bias2, g2, b2, ab, list, nS3, 0);

  // ---- layer 2: xl over S3; xr identity rows < L; aggregate dst < L ----
  gemm_fused_kernel<<<panels128 * 12, 256, 0, stream>>>(ab, wt3, bl3, br3, xl, xr,
                                                        list, nS3, nullptr, nullptr, L);
  agat_kernel<float><<<(L + 3) / 4, 256, 0, stream>>>(
      xl, xr, att3, off, csr, edges, E0, bias3, g3, b3, out_f + in_sizes[0],
      nullptr, nullptr, L);
}

// Round 14
// 204.253 us; speedup vs baseline: 1.4716x; 1.4716x over previous
//
#include <hip/hip_runtime.h>
#include <hip/hip_bf16.h>
#include <math.h>

#define H 768
#define BM 128

typedef __attribute__((ext_vector_type(4))) float f32x4;
typedef __attribute__((ext_vector_type(8))) short bf16x8;

__device__ __forceinline__ float bf2f(unsigned u16v){
  return __uint_as_float((u16v & 0xffffu) << 16);
}
__device__ __forceinline__ unsigned f2bf2(float a, float b){
  __hip_bfloat16 ha = __float2bfloat16(a), hb = __float2bfloat16(b);
  return (unsigned)*(unsigned short*)&ha | ((unsigned)*(unsigned short*)&hb << 16);
}
__device__ __forceinline__ float gelu_exact(float x){
  return 0.5f * x * (1.0f + erff(x * 0.70710678118654752f));
}
__device__ __forceinline__ void gload16(const void* g, void* l){
  __builtin_amdgcn_global_load_lds(
      (const __attribute__((address_space(1))) unsigned int*)g,
      (__attribute__((address_space(3))) unsigned int*)l,
      16, 0, 0);
}
__device__ __forceinline__ float wave_sum(float p){
#pragma unroll
  for (int o = 32; o; o >>= 1) p += __shfl_xor(p, o);
  return p;
}
__device__ __forceinline__ int e_src(const int* ep, int E0, int k){
  return (k < E0) ? ep[k] : (k - E0);
}
__device__ __forceinline__ int e_dst(const int* ep, int E0, int k){
  return (k < E0) ? ep[E0 + k] : (k - E0);
}

// ---------------- LayerNorm + exact GELU over a row LIST (grid-stride) ----------------
__global__ __launch_bounds__(256) void lnw_list_kernel(
    const float* __restrict__ in, const float* __restrict__ g,
    const float* __restrict__ b, __hip_bfloat16* __restrict__ out,
    const int* __restrict__ rlist, const int* __restrict__ np){
  int lim = *np;
  int lane = threadIdx.x & 63;
  for (int i = blockIdx.x * 4 + (threadIdx.x >> 6); i < lim; i += gridDim.x * 4){
    int row = rlist[i];
    const float* rp = in + (size_t)row * H;
    float v[12];
#pragma unroll
    for (int q = 0; q < 3; q++){
      float4 t = *(const float4*)&rp[(lane + q * 64) * 4];
      v[q*4+0] = t.x; v[q*4+1] = t.y; v[q*4+2] = t.z; v[q*4+3] = t.w;
    }
    float s = 0.f;
#pragma unroll
    for (int t = 0; t < 12; t++) s += v[t];
    float mean = wave_sum(s) * (1.0f / H);
    float s2 = 0.f;
#pragma unroll
    for (int t = 0; t < 12; t++){ float d = v[t] - mean; s2 += d * d; }
    float rstd = rsqrtf(wave_sum(s2) * (1.0f / H) + 1e-5f);
    unsigned* op = (unsigned*)(out + (size_t)row * H);
#pragma unroll
    for (int q = 0; q < 3; q++){
      float4 gv = *(const float4*)&g[(lane + q * 64) * 4];
      float4 bv = *(const float4*)&b[(lane + q * 64) * 4];
      float z0 = gelu_exact((v[q*4+0] - mean) * rstd * gv.x + bv.x);
      float z1 = gelu_exact((v[q*4+1] - mean) * rstd * gv.y + bv.y);
      float z2 = gelu_exact((v[q*4+2] - mean) * rstd * gv.z + bv.z);
      float z3 = gelu_exact((v[q*4+3] - mean) * rstd * gv.w + bv.w);
      uint2 pk; pk.x = f2bf2(z0, z1); pk.y = f2bf2(z2, z3);
      *(uint2*)&op[lane * 2 + q * 128] = pk;
    }
  }
}

// ---------------- weight transpose + f32->bf16 (all 4 matrices, z-indexed) ----------------
__global__ __launch_bounds__(256) void wt_bf16_kernel(
    const float* __restrict__ W0, const float* __restrict__ W1,
    const float* __restrict__ W2, const float* __restrict__ W3,
    __hip_bfloat16* __restrict__ T0, __hip_bfloat16* __restrict__ T1,
    __hip_bfloat16* __restrict__ T2, __hip_bfloat16* __restrict__ T3){
  int z = blockIdx.z;
  const float* W = (z == 0) ? W0 : (z == 1) ? W1 : (z == 2) ? W2 : W3;
  __hip_bfloat16* WT = (z == 0) ? T0 : (z == 1) ? T1 : (z == 2) ? T2 : T3;
  __shared__ float tile[32][33];
  int k0 = blockIdx.x * 32, n0 = blockIdx.y * 32;
  int tx = threadIdx.x & 31, ty = threadIdx.x >> 5;   // 32 x 8
#pragma unroll
  for (int i = 0; i < 32; i += 8)
    tile[ty + i][tx] = W[(size_t)(k0 + ty + i) * H + n0 + tx];
  __syncthreads();
#pragma unroll
  for (int i = 0; i < 32; i += 8)
    WT[(size_t)(n0 + ty + i) * H + k0 + tx] = __float2bfloat16(tile[tx][ty + i]);
}

// ---------------- 128x128 4-wave GEMM, dual row-compaction (both layers) ----------------
// [Cl | Cr] = A[...] @ WT[1536,768]^T (+bias). Validated round-4..12 sync
// structure (3-buffer, depth-2, counted vmcnt). xl blocks gather/store rows via
// rmapL (count *nrLp); xr blocks via rmapR (count *nrRp) or identity < MrR.
__global__ __launch_bounds__(256, 3) void gemm_fused_kernel(
    const __hip_bfloat16* __restrict__ A,
    const __hip_bfloat16* __restrict__ WT,
    const float* __restrict__ bl, const float* __restrict__ br,
    __hip_bfloat16* __restrict__ Cl, __hip_bfloat16* __restrict__ Cr,
    const int* __restrict__ rmapL, const int* __restrict__ nrLp,
    const int* __restrict__ rmapR, const int* __restrict__ nrRp, int MrR){
  __shared__ char smem[49152];          // 3 x (As 8KB | Bs 8KB)

  int wgid = blockIdx.x;
  int panel = wgid / 12, colblk = wgid % 12;   // identity: spreads active blocks
  int row0 = panel * BM;
  const bool is_r = colblk >= 6;
  const int* rmap = is_r ? rmapR : rmapL;
  int nr = is_r ? (rmapR ? *nrRp : MrR) : *nrLp;
  if (row0 >= nr) return;
  const bool remap = (rmap != nullptr);

  const int t = threadIdx.x;
  const int sr = t >> 2;
  const int scs = (((t & 3) ^ ((sr >> 1) & 3)) * 8);
  const int t16 = t * 16;
  int ra0 = min(row0 + sr, nr - 1), ra1 = min(row0 + sr + 64, nr - 1);
  if (remap){ ra0 = rmap[ra0]; ra1 = rmap[ra1]; }
  const __hip_bfloat16* pa0 = A + (size_t)ra0 * H + scs;
  const __hip_bfloat16* pa1 = A + (size_t)ra1 * H + scs;
  const __hip_bfloat16* pb0 = WT + (size_t)(colblk * 128 + sr) * H + scs;
  const __hip_bfloat16* pb1 = pb0 + (size_t)64 * H;

  const int l = t & 63, w = t >> 6;
  const int wm = (w >> 1) * 64, wn = (w & 1) * 64;
  const int r0 = l & 15;
  const int kcs2 = (((l >> 4) ^ ((r0 >> 1) & 3)) * 16);

  f32x4 acc[4][4];
#pragma unroll
  for (int m = 0; m < 4; m++)
#pragma unroll
    for (int n = 0; n < 4; n++) acc[m][n] = (f32x4){0.f, 0.f, 0.f, 0.f};

#define STAGE(kt, b) do{                                   \
    int _k0 = (kt) * 32;                                   \
    char* _bs = smem + (b) * 16384;                        \
    gload16(pa0 + _k0, _bs + t16);                         \
    gload16(pa1 + _k0, _bs + 4096 + t16);                  \
    gload16(pb0 + _k0, _bs + 8192 + t16);                  \
    gload16(pb1 + _k0, _bs + 12288 + t16);                 \
  }while(0)

  STAGE(0, 0);
  STAGE(1, 1);

  for (int kt = 0; kt < 24; kt++){
    if (kt < 23) asm volatile("s_waitcnt vmcnt(4)" ::: "memory");
    else         asm volatile("s_waitcnt vmcnt(0)" ::: "memory");
    __builtin_amdgcn_s_barrier();
    __builtin_amdgcn_sched_barrier(0);
    if (kt + 2 < 24) STAGE(kt + 2, (kt + 2) % 3);
    const char* base = smem + (kt % 3) * 16384;
    bf16x8 af[4], bfr[4];
#pragma unroll
    for (int m = 0; m < 4; m++)
      af[m]  = *(const bf16x8*)(base + (wm + m * 16 + r0) * 64 + kcs2);
#pragma unroll
    for (int n = 0; n < 4; n++)
      bfr[n] = *(const bf16x8*)(base + 8192 + (wn + n * 16 + r0) * 64 + kcs2);
#pragma unroll
    for (int m = 0; m < 4; m++)
#pragma unroll
      for (int n = 0; n < 4; n++)
        acc[m][n] = __builtin_amdgcn_mfma_f32_16x16x32_bf16(af[m], bfr[n], acc[m][n], 0, 0, 0);
  }
#undef STAGE

  __syncthreads();
  const int rgrp = (l >> 4) * 4;
  const float* bp = is_r ? br : bl;
  const int cb = (is_r ? colblk - 6 : colblk) * 128;
#pragma unroll
  for (int n = 0; n < 4; n++){
    int lc = wn + n * 16 + r0;
    float bb = bp[cb + lc];
#pragma unroll
    for (int m = 0; m < 4; m++){
#pragma unroll
      for (int jj = 0; jj < 4; jj++){
        int lr = wm + m * 16 + rgrp + jj;
        int byte = lr * 256 + ((lc * 2) ^ (((lr >> 2) & 3) << 5));
        *(__hip_bfloat16*)(smem + byte) = __float2bfloat16(acc[m][n][jj] + bb);
      }
    }
  }
  __syncthreads();
  __hip_bfloat16* C = is_r ? Cr : Cl;
#pragma unroll
  for (int p = 0; p < 8; p++){
    int ba = p * 4096 + t16;
    int lr = ba >> 8, inner = ba & 255;
    int gr = row0 + lr;
    if (gr >= nr) continue;
    int orow = remap ? rmap[gr] : gr;
    uint4 v = *(const uint4*)(smem + lr * 256 + (inner ^ (((lr >> 2) & 3) << 5)));
    *(uint4*)(C + (size_t)orow * H + cb + (inner >> 1)) = v;
  }
}

// ---------------- CSR build + S3 marking (dst<L srcs) ----------------
__global__ __launch_bounds__(256) void count_mark_kernel(const int* __restrict__ ep,
                                                         int E0, int E, int L,
                                                         int* __restrict__ cnt,
                                                         int* __restrict__ flag){
  int k = blockIdx.x * 256 + threadIdx.x;
  if (k >= E) return;
  int d = e_dst(ep, E0, k);
  atomicAdd(&cnt[d], 1);
  if (d < L) flag[e_src(ep, E0, k)] = 1;       // S3; benign same-value race
}

// S2 marking: srcs of edges whose dst is in S3 (requires flag complete)
__global__ __launch_bounds__(256) void mark2_kernel(const int* __restrict__ ep,
                                                    int E0, int E,
                                                    const int* __restrict__ flag,
                                                    int* __restrict__ flag2){
  int k = blockIdx.x * 256 + threadIdx.x;
  if (k >= E) return;
  if (flag[e_dst(ep, E0, k)]) flag2[e_src(ep, E0, k)] = 1;
}

// tri chunk-scan: q0 cnt->off/sums, q1 flag->fpos/fsums, q2 flag2->fpos2/fsums2
__global__ __launch_bounds__(1024) void scan1_tri_kernel(
    const int* __restrict__ a0, int* __restrict__ o0, int* __restrict__ s0,
    const int* __restrict__ a1, int* __restrict__ o1, int* __restrict__ s1,
    const int* __restrict__ a2, int* __restrict__ o2, int* __restrict__ s2, int n){
  __shared__ int lds[1024];
  const int* as[3] = {a0, a1, a2};
  int* os[3] = {o0, o1, o2};
  int* ss[3] = {s0, s1, s2};
  int tid = threadIdx.x;
  int gi = blockIdx.x * 1024 + tid;
  for (int q = 0; q < 3; q++){
    __syncthreads();
    int v = (gi < n) ? as[q][gi] : 0;
    lds[tid] = v;
    __syncthreads();
    for (int o = 1; o < 1024; o <<= 1){
      int tv = (tid >= o) ? lds[tid - o] : 0;
      __syncthreads();
      lds[tid] += tv;
      __syncthreads();
    }
    if (gi < n) os[q][gi] = lds[tid] - v;
    if (tid == 1023) ss[q][blockIdx.x] = lds[1023];
  }
}

__global__ void scan2_tri_kernel(int* __restrict__ s0, int* __restrict__ o0,
                                 int* __restrict__ s1, int* __restrict__ o1,
                                 int* __restrict__ s2, int* __restrict__ o2,
                                 int nb, int n){
  int lane = threadIdx.x;                      // single wave of 64, nb <= 64
  int* ss[3] = {s0, s1, s2};
  int* os[3] = {o0, o1, o2};
  for (int q = 0; q < 3; q++){
    int v = (lane < nb) ? ss[q][lane] : 0;
    int incl = v;
#pragma unroll
    for (int o = 1; o < 64; o <<= 1){
      int t = __shfl_up(incl, o);
      if (lane >= o) incl += t;
    }
    if (lane < nb) ss[q][lane] = incl - v;
    if (lane == nb - 1) os[q][n] = incl;
  }
}

// apply block offsets; emit cur copy and both ordered compaction lists
__global__ __launch_bounds__(1024) void scan3_tri_kernel(
    int* __restrict__ off, int* __restrict__ cur, const int* __restrict__ sums,
    int* __restrict__ fpos, const int* __restrict__ fsums,
    const int* __restrict__ flag, int* __restrict__ list,
    int* __restrict__ fpos2, const int* __restrict__ fsums2,
    const int* __restrict__ flag2, int* __restrict__ list2, int n){
  int gi = blockIdx.x * 1024 + threadIdx.x;
  if (gi < n){
    int v = off[gi] + sums[blockIdx.x];
    off[gi] = v;
    cur[gi] = v;
    int fp = fpos[gi] + fsums[blockIdx.x];
    fpos[gi] = fp;
    if (flag[gi]) list[fp] = gi;
    int fp2 = fpos2[gi] + fsums2[blockIdx.x];
    fpos2[gi] = fp2;
    if (flag2[gi]) list2[fp2] = gi;
  }
}

// fill CSR — only edges whose dst is aggregated (dst in S3; L ⊆ S3 via self-loops)
__global__ __launch_bounds__(256) void fill_kernel(const int* __restrict__ ep, int E0, int E,
                                                   const int* __restrict__ flag,
                                                   int* __restrict__ cur, int* __restrict__ csr){
  int k = blockIdx.x * 256 + threadIdx.x;
  if (k >= E) return;
  int d = e_dst(ep, E0, k);
  if (flag[d]) csr[atomicAdd(&cur[d], 1)] = k;
}

// ---------------- fused GAT attend+aggregate+LN+GELU: one WAVE per dst (grid-stride) ----------------
template<typename OutT>
__global__ __launch_bounds__(256) void agat_kernel(
    const __hip_bfloat16* __restrict__ xl, const __hip_bfloat16* __restrict__ xr,
    const float* __restrict__ att, const int* __restrict__ off,
    const int* __restrict__ csr, const int* __restrict__ ep, int E0,
    const float* __restrict__ bias, const float* __restrict__ g,
    const float* __restrict__ b, OutT* __restrict__ out,
    const int* __restrict__ dlist, const int* __restrict__ ndp, int ndst){
  int lim = dlist ? *ndp : ndst;
  int lane = threadIdx.x & 63;
  for (int i = blockIdx.x * 4 + (threadIdx.x >> 6); i < lim; i += gridDim.x * 4){
    int d = dlist ? dlist[i] : i;
    float xrv[12], attv[12];
    const unsigned* pr = (const unsigned*)(xr + (size_t)d * H);
#pragma unroll
    for (int q = 0; q < 3; q++){
      uint2 vr = *(const uint2*)&pr[lane * 2 + q * 128];
      float4 av = *(const float4*)&att[(lane + q * 64) * 4];
      xrv[q*4+0] = bf2f(vr.x); xrv[q*4+1] = bf2f(vr.x >> 16);
      xrv[q*4+2] = bf2f(vr.y); xrv[q*4+3] = bf2f(vr.y >> 16);
      attv[q*4+0] = av.x; attv[q*4+1] = av.y; attv[q*4+2] = av.z; attv[q*4+3] = av.w;
    }
    float m = -INFINITY, den = 0.f, acc[12];
#pragma unroll
    for (int t = 0; t < 12; t++) acc[t] = 0.f;
    int j0 = off[d], j1 = off[d + 1];
    int sj = (j0 < j1) ? e_src(ep, E0, csr[j0]) : 0;   // src prefetch pipeline
    for (int j = j0; j < j1; j++){
      int s_ = sj;
      if (j + 1 < j1) sj = e_src(ep, E0, csr[j + 1]);
      const unsigned* pl = (const unsigned*)(xl + (size_t)s_ * H);
      float xv[12];
#pragma unroll
      for (int q = 0; q < 3; q++){
        uint2 vl = *(const uint2*)&pl[lane * 2 + q * 128];
        xv[q*4+0] = bf2f(vl.x); xv[q*4+1] = bf2f(vl.x >> 16);
        xv[q*4+2] = bf2f(vl.y); xv[q*4+3] = bf2f(vl.y >> 16);
      }
      float p = 0.f;
#pragma unroll
      for (int t = 0; t < 12; t++){
        float v = xv[t] + xrv[t];
        v = (v > 0.f) ? v : 0.2f * v;
        p += v * attv[t];
      }
      p = wave_sum(p);
      float mn = fmaxf(m, p);
      float sc = __expf(m - mn), wgt = __expf(p - mn);
      den = den * sc + wgt;
#pragma unroll
      for (int t = 0; t < 12; t++) acc[t] = acc[t] * sc + wgt * xv[t];
      m = mn;
    }
    float inv = 1.0f / den;
    float y[12];
    float s1 = 0.f;
#pragma unroll
    for (int q = 0; q < 3; q++){
      float4 bv = *(const float4*)&bias[(lane + q * 64) * 4];
      y[q*4+0] = acc[q*4+0] * inv + bv.x;
      y[q*4+1] = acc[q*4+1] * inv + bv.y;
      y[q*4+2] = acc[q*4+2] * inv + bv.z;
      y[q*4+3] = acc[q*4+3] * inv + bv.w;
    }
#pragma unroll
    for (int t = 0; t < 12; t++) s1 += y[t];
    float mean = wave_sum(s1) * (1.0f / H);
    float s2 = 0.f;
#pragma unroll
    for (int t = 0; t < 12; t++){ float dt = y[t] - mean; s2 += dt * dt; }
    float rstd = rsqrtf(wave_sum(s2) * (1.0f / H) + 1e-5f);
    OutT* op = out + (size_t)d * H;
#pragma unroll
    for (int q = 0; q < 3; q++){
      float4 gv = *(const float4*)&g[(lane + q * 64) * 4];
      float4 bv = *(const float4*)&b[(lane + q * 64) * 4];
      float z0 = gelu_exact((y[q*4+0] - mean) * rstd * gv.x + bv.x);
      float z1 = gelu_exact((y[q*4+1] - mean) * rstd * gv.y + bv.y);
      float z2 = gelu_exact((y[q*4+2] - mean) * rstd * gv.z + bv.z);
      float z3 = gelu_exact((y[q*4+3] - mean) * rstd * gv.w + bv.w);
      if constexpr (sizeof(OutT) == 2){
        uint2 pk; pk.x = f2bf2(z0, z1); pk.y = f2bf2(z2, z3);
        *(uint2*)((unsigned*)op + lane * 2 + q * 128) = pk;
      } else {
        float4 fv; fv.x = z0; fv.y = z1; fv.z = z2; fv.w = z3;
        *(float4*)&op[(lane + q * 64) * 4] = fv;
      }
    }
  }
}

extern "C" void kernel_launch(void* const* d_in, const int* in_sizes, int n_in,
                              void* d_out, int out_size, void* d_ws, size_t ws_size,
                              hipStream_t stream){
  const float* emb   = (const float*)d_in[0];
  const float* feats = (const float*)d_in[1];
  const int*   edges = (const int*)d_in[2];
  const float* Wl2 = (const float*)d_in[4],  *bl2 = (const float*)d_in[5];
  const float* Wr2 = (const float*)d_in[6],  *br2 = (const float*)d_in[7];
  const float* att2= (const float*)d_in[8],  *bias2=(const float*)d_in[9];
  const float* Wl3 = (const float*)d_in[10], *bl3 = (const float*)d_in[11];
  const float* Wr3 = (const float*)d_in[12], *br3 = (const float*)d_in[13];
  const float* att3= (const float*)d_in[14], *bias3=(const float*)d_in[15];
  const float* g1 = (const float*)d_in[16], *b1 = (const float*)d_in[17];
  const float* g2 = (const float*)d_in[18], *b2 = (const float*)d_in[19];
  const float* g3 = (const float*)d_in[20], *b3 = (const float*)d_in[21];

  const int N  = in_sizes[1] / H;             // 50000
  const int E0 = in_sizes[2] / 2;             // 100000
  const int E  = E0 + N;                      // 150000
  const int L  = 4096;                        // labels_size
  const int Mpad = ((N + 127) / 128) * 128;            // 50048 rows capacity
  const int panels128 = Mpad / BM;                     // 391
  const int nchunk = (N + 1023) / 1024;                // 49 (<= 64)

  __hip_bfloat16* ab  = (__hip_bfloat16*)d_ws;          // [Mpad][H] GEMM input
  __hip_bfloat16* xl  = ab + (size_t)Mpad * H;          // [Mpad][H]
  __hip_bfloat16* xr  = xl + (size_t)Mpad * H;          // [Mpad][H]
  __hip_bfloat16* wt2 = xr + (size_t)Mpad * H;          // [1536][H]
  __hip_bfloat16* wt3 = wt2 + (size_t)2 * H * H;        // [1536][H]
  int* cnt   = (int*)(wt3 + (size_t)2 * H * H);         // [N]   (zeroed together:)
  int* flag  = cnt + N;                                 // [N]   S3 flags
  int* flag2 = flag + N;                                // [N]   S2 flags
  int* off   = flag2 + N;                               // [N+1]
  int* cur   = off + N + 1;                             // [N]
  int* csr   = cur + N;                                 // [E]
  int* sums  = csr + E;                                 // [64]
  int* fpos  = sums + 64;                               // [N+1] S3 scan (+count)
  int* fsums = fpos + N + 1;                            // [64]
  int* fpos2 = fsums + 64;                              // [N+1] S2 scan (+count)
  int* fsums2= fpos2 + N + 1;                           // [64]
  int* list  = fsums2 + 64;                             // [N]   S3 row list
  int* list2 = list + N;                                // [N]   S2 row list

  float* out_f = (float*)d_out;

  // output 0: passthrough copy of input_embeddings
  hipMemcpyAsync(out_f, emb, (size_t)in_sizes[0] * sizeof(float),
                 hipMemcpyDeviceToDevice, stream);

  // CSR by dst + backward-slice row sets S3 (layer-2 srcs) and S2 (layer-1 srcs)
  hipMemsetAsync(cnt, 0, (size_t)3 * N * sizeof(int), stream);
  count_mark_kernel<<<(E + 255) / 256, 256, 0, stream>>>(edges, E0, E, L, cnt, flag);
  mark2_kernel<<<(E + 255) / 256, 256, 0, stream>>>(edges, E0, E, flag, flag2);
  scan1_tri_kernel<<<nchunk, 1024, 0, stream>>>(cnt, off, sums, flag, fpos, fsums,
                                                flag2, fpos2, fsums2, N);
  scan2_tri_kernel<<<1, 64, 0, stream>>>(sums, off, fsums, fpos, fsums2, fpos2, nchunk, N);
  scan3_tri_kernel<<<nchunk, 1024, 0, stream>>>(off, cur, sums, fpos, fsums, flag, list,
                                                fpos2, fsums2, flag2, list2, N);
  fill_kernel<<<(E + 255) / 256, 256, 0, stream>>>(edges, E0, E, flag, cur, csr);

  // weights -> bf16 transposed, concatenated [Wl^T ; Wr^T] (one launch)
  dim3 wgrid(H / 32, H / 32, 4);
  wt_bf16_kernel<<<wgrid, 256, 0, stream>>>(Wl2, Wr2, Wl3, Wr3,
                                            wt2, wt2 + (size_t)H * H,
                                            wt3, wt3 + (size_t)H * H);

  const int* nS3 = fpos + N;    // |S3|
  const int* nS2 = fpos2 + N;   // |S2|

  // ---- layer 1 (sliced): LN over S2; xl over S2, xr over S3; aggregate dst in S3 ----
  lnw_list_kernel<<<2048, 256, 0, stream>>>(feats, g1, b1, ab, list2, nS2);
  gemm_fused_kernel<<<panels128 * 12, 256, 0, stream>>>(ab, wt2, bl2, br2, xl, xr,
                                                        list2, nS2, list, nS3, 0);
  agat_kernel<__hip_bfloat16><<<2048, 256, 0, stream>>>(
      xl, xr, att2, off, csr, edges, E0, bias2, g2, b2, ab, list, nS3, 0);

  // ---- layer 2: xl over S3; xr identity rows < L; aggregate dst < L ----
  gemm_fused_kernel<<<panels128 * 12, 256, 0, stream>>>(ab, wt3, bl3, br3, xl, xr,
                                                        list, nS3, nullptr, nullptr, L);
  agat_kernel<float><<<(L + 3) / 4, 256, 0, stream>>>(
      xl, xr, att3, off, csr, edges, E0, bias3, g3, b3, out_f + in_sizes[0],
      nullptr, nullptr, L);
}

// Round 16
// 200.782 us; speedup vs baseline: 1.4970x; 1.0173x over previous
//
#include <hip/hip_runtime.h>
#include <hip/hip_bf16.h>
#include <math.h>

#define H 768
#define BM 128

typedef __attribute__((ext_vector_type(4))) float f32x4;
typedef __attribute__((ext_vector_type(8))) short bf16x8;

__device__ __forceinline__ float bf2f(unsigned u16v){
  return __uint_as_float((u16v & 0xffffu) << 16);
}
__device__ __forceinline__ unsigned f2bf2(float a, float b){
  __hip_bfloat16 ha = __float2bfloat16(a), hb = __float2bfloat16(b);
  return (unsigned)*(unsigned short*)&ha | ((unsigned)*(unsigned short*)&hb << 16);
}
__device__ __forceinline__ float gelu_exact(float x){
  return 0.5f * x * (1.0f + erff(x * 0.70710678118654752f));
}
__device__ __forceinline__ void gload16(const void* g, void* l){
  __builtin_amdgcn_global_load_lds(
      (const __attribute__((address_space(1))) unsigned int*)g,
      (__attribute__((address_space(3))) unsigned int*)l,
      16, 0, 0);
}
__device__ __forceinline__ float wave_sum(float p){
#pragma unroll
  for (int o = 32; o; o >>= 1) p += __shfl_xor(p, o);
  return p;
}
__device__ __forceinline__ int e_src(const int* ep, int E0, int k){
  return (k < E0) ? ep[k] : (k - E0);
}
__device__ __forceinline__ int e_dst(const int* ep, int E0, int k){
  return (k < E0) ? ep[E0 + k] : (k - E0);
}

// ---------------- LayerNorm + exact GELU over a row LIST (grid-stride) ----------------
__global__ __launch_bounds__(256) void lnw_list_kernel(
    const float* __restrict__ in, const float* __restrict__ g,
    const float* __restrict__ b, __hip_bfloat16* __restrict__ out,
    const int* __restrict__ rlist, const int* __restrict__ np){
  int lim = *np;
  int lane = threadIdx.x & 63;
  for (int i = blockIdx.x * 4 + (threadIdx.x >> 6); i < lim; i += gridDim.x * 4){
    int row = rlist[i];
    const float* rp = in + (size_t)row * H;
    float v[12];
#pragma unroll
    for (int q = 0; q < 3; q++){
      float4 t = *(const float4*)&rp[(lane + q * 64) * 4];
      v[q*4+0] = t.x; v[q*4+1] = t.y; v[q*4+2] = t.z; v[q*4+3] = t.w;
    }
    float s = 0.f;
#pragma unroll
    for (int t = 0; t < 12; t++) s += v[t];
    float mean = wave_sum(s) * (1.0f / H);
    float s2 = 0.f;
#pragma unroll
    for (int t = 0; t < 12; t++){ float d = v[t] - mean; s2 += d * d; }
    float rstd = rsqrtf(wave_sum(s2) * (1.0f / H) + 1e-5f);
    unsigned* op = (unsigned*)(out + (size_t)row * H);
#pragma unroll
    for (int q = 0; q < 3; q++){
      float4 gv = *(const float4*)&g[(lane + q * 64) * 4];
      float4 bv = *(const float4*)&b[(lane + q * 64) * 4];
      float z0 = gelu_exact((v[q*4+0] - mean) * rstd * gv.x + bv.x);
      float z1 = gelu_exact((v[q*4+1] - mean) * rstd * gv.y + bv.y);
      float z2 = gelu_exact((v[q*4+2] - mean) * rstd * gv.z + bv.z);
      float z3 = gelu_exact((v[q*4+3] - mean) * rstd * gv.w + bv.w);
      uint2 pk; pk.x = f2bf2(z0, z1); pk.y = f2bf2(z2, z3);
      *(uint2*)&op[lane * 2 + q * 128] = pk;
    }
  }
}

// ---------------- weight transpose + f32->bf16 (all 4 matrices, z-indexed) ----------------
__global__ __launch_bounds__(256) void wt_bf16_kernel(
    const float* __restrict__ W0, const float* __restrict__ W1,
    const float* __restrict__ W2, const float* __restrict__ W3,
    __hip_bfloat16* __restrict__ T0, __hip_bfloat16* __restrict__ T1,
    __hip_bfloat16* __restrict__ T2, __hip_bfloat16* __restrict__ T3){
  int z = blockIdx.z;
  const float* W = (z == 0) ? W0 : (z == 1) ? W1 : (z == 2) ? W2 : W3;
  __hip_bfloat16* WT = (z == 0) ? T0 : (z == 1) ? T1 : (z == 2) ? T2 : T3;
  __shared__ float tile[32][33];
  int k0 = blockIdx.x * 32, n0 = blockIdx.y * 32;
  int tx = threadIdx.x & 31, ty = threadIdx.x >> 5;   // 32 x 8
#pragma unroll
  for (int i = 0; i < 32; i += 8)
    tile[ty + i][tx] = W[(size_t)(k0 + ty + i) * H + n0 + tx];
  __syncthreads();
#pragma unroll
  for (int i = 0; i < 32; i += 8)
    WT[(size_t)(n0 + ty + i) * H + k0 + tx] = __float2bfloat16(tile[tx][ty + i]);
}

// ---------------- 128x128 4-wave GEMM, dual row-compaction (round-14 validated) ----------------
// [Cl | Cr] = A[...] @ WT[1536,768]^T (+bias). 3-buffer, depth-2, counted vmcnt.
// xl blocks gather/store rows via rmapL (count *nrLp); xr blocks via rmapR
// (count *nrRp) or identity < MrR.
__global__ __launch_bounds__(256, 3) void gemm_fused_kernel(
    const __hip_bfloat16* __restrict__ A,
    const __hip_bfloat16* __restrict__ WT,
    const float* __restrict__ bl, const float* __restrict__ br,
    __hip_bfloat16* __restrict__ Cl, __hip_bfloat16* __restrict__ Cr,
    const int* __restrict__ rmapL, const int* __restrict__ nrLp,
    const int* __restrict__ rmapR, const int* __restrict__ nrRp, int MrR){
  __shared__ char smem[49152];          // 3 x (As 8KB | Bs 8KB)

  int wgid = blockIdx.x;
  int panel = wgid / 12, colblk = wgid % 12;   // identity: spreads active blocks
  int row0 = panel * BM;
  const bool is_r = colblk >= 6;
  const int* rmap = is_r ? rmapR : rmapL;
  int nr = is_r ? (rmapR ? *nrRp : MrR) : *nrLp;
  if (row0 >= nr) return;
  const bool remap = (rmap != nullptr);

  const int t = threadIdx.x;
  const int sr = t >> 2;
  const int scs = (((t & 3) ^ ((sr >> 1) & 3)) * 8);
  const int t16 = t * 16;
  int ra0 = min(row0 + sr, nr - 1), ra1 = min(row0 + sr + 64, nr - 1);
  if (remap){ ra0 = rmap[ra0]; ra1 = rmap[ra1]; }
  const __hip_bfloat16* pa0 = A + (size_t)ra0 * H + scs;
  const __hip_bfloat16* pa1 = A + (size_t)ra1 * H + scs;
  const __hip_bfloat16* pb0 = WT + (size_t)(colblk * 128 + sr) * H + scs;
  const __hip_bfloat16* pb1 = pb0 + (size_t)64 * H;

  const int l = t & 63, w = t >> 6;
  const int wm = (w >> 1) * 64, wn = (w & 1) * 64;
  const int r0 = l & 15;
  const int kcs2 = (((l >> 4) ^ ((r0 >> 1) & 3)) * 16);

  f32x4 acc[4][4];
#pragma unroll
  for (int m = 0; m < 4; m++)
#pragma unroll
    for (int n = 0; n < 4; n++) acc[m][n] = (f32x4){0.f, 0.f, 0.f, 0.f};

#define STAGE(kt, b) do{                                   \
    int _k0 = (kt) * 32;                                   \
    char* _bs = smem + (b) * 16384;                        \
    gload16(pa0 + _k0, _bs + t16);                         \
    gload16(pa1 + _k0, _bs + 4096 + t16);                  \
    gload16(pb0 + _k0, _bs + 8192 + t16);                  \
    gload16(pb1 + _k0, _bs + 12288 + t16);                 \
  }while(0)

  STAGE(0, 0);
  STAGE(1, 1);

  for (int kt = 0; kt < 24; kt++){
    if (kt < 23) asm volatile("s_waitcnt vmcnt(4)" ::: "memory");
    else         asm volatile("s_waitcnt vmcnt(0)" ::: "memory");
    __builtin_amdgcn_s_barrier();
    __builtin_amdgcn_sched_barrier(0);
    if (kt + 2 < 24) STAGE(kt + 2, (kt + 2) % 3);
    const char* base = smem + (kt % 3) * 16384;
    bf16x8 af[4], bfr[4];
#pragma unroll
    for (int m = 0; m < 4; m++)
      af[m]  = *(const bf16x8*)(base + (wm + m * 16 + r0) * 64 + kcs2);
#pragma unroll
    for (int n = 0; n < 4; n++)
      bfr[n] = *(const bf16x8*)(base + 8192 + (wn + n * 16 + r0) * 64 + kcs2);
#pragma unroll
    for (int m = 0; m < 4; m++)
#pragma unroll
      for (int n = 0; n < 4; n++)
        acc[m][n] = __builtin_amdgcn_mfma_f32_16x16x32_bf16(af[m], bfr[n], acc[m][n], 0, 0, 0);
  }
#undef STAGE

  __syncthreads();
  const int rgrp = (l >> 4) * 4;
  const float* bp = is_r ? br : bl;
  const int cb = (is_r ? colblk - 6 : colblk) * 128;
#pragma unroll
  for (int n = 0; n < 4; n++){
    int lc = wn + n * 16 + r0;
    float bb = bp[cb + lc];
#pragma unroll
    for (int m = 0; m < 4; m++){
#pragma unroll
      for (int jj = 0; jj < 4; jj++){
        int lr = wm + m * 16 + rgrp + jj;
        int byte = lr * 256 + ((lc * 2) ^ (((lr >> 2) & 3) << 5));
        *(__hip_bfloat16*)(smem + byte) = __float2bfloat16(acc[m][n][jj] + bb);
      }
    }
  }
  __syncthreads();
  __hip_bfloat16* C = is_r ? Cr : Cl;
#pragma unroll
  for (int p = 0; p < 8; p++){
    int ba = p * 4096 + t16;
    int lr = ba >> 8, inner = ba & 255;
    int gr = row0 + lr;
    if (gr >= nr) continue;
    int orow = remap ? rmap[gr] : gr;
    uint4 v = *(const uint4*)(smem + lr * 256 + (inner ^ (((lr >> 2) & 3) << 5)));
    *(uint4*)(C + (size_t)orow * H + cb + (inner >> 1)) = v;
  }
}

// ---------------- S3 marking (srcs of dst<L edges) ----------------
__global__ __launch_bounds__(256) void mark_s3_kernel(const int* __restrict__ ep,
                                                      int E0, int E, int L,
                                                      int* __restrict__ flag){
  int k = blockIdx.x * 256 + threadIdx.x;
  if (k >= E) return;
  if (e_dst(ep, E0, k) < L) flag[e_src(ep, E0, k)] = 1;  // benign same-value race
}

// S2 marking + filtered CSR counting (only S3-dst segments are ever read back)
__global__ __launch_bounds__(256) void mark2_count_kernel(const int* __restrict__ ep,
                                                          int E0, int E,
                                                          const int* __restrict__ flag,
                                                          int* __restrict__ flag2,
                                                          int* __restrict__ cnt){
  int k = blockIdx.x * 256 + threadIdx.x;
  if (k >= E) return;
  int d = e_dst(ep, E0, k);
  if (flag[d]){
    flag2[e_src(ep, E0, k)] = 1;
    atomicAdd(&cnt[d], 1);
  }
}

// tri chunk-scan: q0 cnt->off/sums, q1 flag->fpos/fsums, q2 flag2->fpos2/fsums2
__global__ __launch_bounds__(1024) void scan1_tri_kernel(
    const int* __restrict__ a0, int* __restrict__ o0, int* __restrict__ s0,
    const int* __restrict__ a1, int* __restrict__ o1, int* __restrict__ s1,
    const int* __restrict__ a2, int* __restrict__ o2, int* __restrict__ s2, int n){
  __shared__ int lds[1024];
  const int* as[3] = {a0, a1, a2};
  int* os[3] = {o0, o1, o2};
  int* ss[3] = {s0, s1, s2};
  int tid = threadIdx.x;
  int gi = blockIdx.x * 1024 + tid;
  for (int q = 0; q < 3; q++){
    __syncthreads();
    int v = (gi < n) ? as[q][gi] : 0;
    lds[tid] = v;
    __syncthreads();
    for (int o = 1; o < 1024; o <<= 1){
      int tv = (tid >= o) ? lds[tid - o] : 0;
      __syncthreads();
      lds[tid] += tv;
      __syncthreads();
    }
    if (gi < n) os[q][gi] = lds[tid] - v;
    if (tid == 1023) ss[q][blockIdx.x] = lds[1023];
  }
}

__global__ void scan2_tri_kernel(int* __restrict__ s0, int* __restrict__ o0,
                                 int* __restrict__ s1, int* __restrict__ o1,
                                 int* __restrict__ s2, int* __restrict__ o2,
                                 int nb, int n){
  int lane = threadIdx.x;                      // single wave of 64, nb <= 64
  int* ss[3] = {s0, s1, s2};
  int* os[3] = {o0, o1, o2};
  for (int q = 0; q < 3; q++){
    int v = (lane < nb) ? ss[q][lane] : 0;
    int incl = v;
#pragma unroll
    for (int o = 1; o < 64; o <<= 1){
      int t = __shfl_up(incl, o);
      if (lane >= o) incl += t;
    }
    if (lane < nb) ss[q][lane] = incl - v;
    if (lane == nb - 1) os[q][n] = incl;
  }
}

// apply block offsets; emit cur copy and both ordered compaction lists
__global__ __launch_bounds__(1024) void scan3_tri_kernel(
    int* __restrict__ off, int* __restrict__ cur, const int* __restrict__ sums,
    int* __restrict__ fpos, const int* __restrict__ fsums,
    const int* __restrict__ flag, int* __restrict__ list,
    int* __restrict__ fpos2, const int* __restrict__ fsums2,
    const int* __restrict__ flag2, int* __restrict__ list2, int n){
  int gi = blockIdx.x * 1024 + threadIdx.x;
  if (gi < n){
    int v = off[gi] + sums[blockIdx.x];
    off[gi] = v;
    cur[gi] = v;
    int fp = fpos[gi] + fsums[blockIdx.x];
    fpos[gi] = fp;
    if (flag[gi]) list[fp] = gi;
    int fp2 = fpos2[gi] + fsums2[blockIdx.x];
    fpos2[gi] = fp2;
    if (flag2[gi]) list2[fp2] = gi;
  }
}

// fill CSR — only edges whose dst is aggregated (dst in S3; L ⊆ S3 via self-loops)
__global__ __launch_bounds__(256) void fill_kernel(const int* __restrict__ ep, int E0, int E,
                                                   const int* __restrict__ flag,
                                                   int* __restrict__ cur, int* __restrict__ csr){
  int k = blockIdx.x * 256 + threadIdx.x;
  if (k >= E) return;
  int d = e_dst(ep, E0, k);
  if (flag[d]) csr[atomicAdd(&cur[d], 1)] = k;
}

// ---------------- fused GAT attend+aggregate+LN+GELU: one WAVE per dst (grid-stride) ----------------
template<typename OutT>
__global__ __launch_bounds__(256) void agat_kernel(
    const __hip_bfloat16* __restrict__ xl, const __hip_bfloat16* __restrict__ xr,
    const float* __restrict__ att, const int* __restrict__ off,
    const int* __restrict__ csr, const int* __restrict__ ep, int E0,
    const float* __restrict__ bias, const float* __restrict__ g,
    const float* __restrict__ b, OutT* __restrict__ out,
    const int* __restrict__ dlist, const int* __restrict__ ndp, int ndst){
  int lim = dlist ? *ndp : ndst;
  int lane = threadIdx.x & 63;
  for (int i = blockIdx.x * 4 + (threadIdx.x >> 6); i < lim; i += gridDim.x * 4){
    int d = dlist ? dlist[i] : i;
    float xrv[12], attv[12];
    const unsigned* pr = (const unsigned*)(xr + (size_t)d * H);
#pragma unroll
    for (int q = 0; q < 3; q++){
      uint2 vr = *(const uint2*)&pr[lane * 2 + q * 128];
      float4 av = *(const float4*)&att[(lane + q * 64) * 4];
      xrv[q*4+0] = bf2f(vr.x); xrv[q*4+1] = bf2f(vr.x >> 16);
      xrv[q*4+2] = bf2f(vr.y); xrv[q*4+3] = bf2f(vr.y >> 16);
      attv[q*4+0] = av.x; attv[q*4+1] = av.y; attv[q*4+2] = av.z; attv[q*4+3] = av.w;
    }
    float m = -INFINITY, den = 0.f, acc[12];
#pragma unroll
    for (int t = 0; t < 12; t++) acc[t] = 0.f;
    int j0 = off[d], j1 = off[d + 1];
    int sj = (j0 < j1) ? e_src(ep, E0, csr[j0]) : 0;   // src prefetch pipeline
    for (int j = j0; j < j1; j++){
      int s_ = sj;
      if (j + 1 < j1) sj = e_src(ep, E0, csr[j + 1]);
      const unsigned* pl = (const unsigned*)(xl + (size_t)s_ * H);
      float xv[12];
#pragma unroll
      for (int q = 0; q < 3; q++){
        uint2 vl = *(const uint2*)&pl[lane * 2 + q * 128];
        xv[q*4+0] = bf2f(vl.x); xv[q*4+1] = bf2f(vl.x >> 16);
        xv[q*4+2] = bf2f(vl.y); xv[q*4+3] = bf2f(vl.y >> 16);
      }
      float p = 0.f;
#pragma unroll
      for (int t = 0; t < 12; t++){
        float v = xv[t] + xrv[t];
        v = (v > 0.f) ? v : 0.2f * v;
        p += v * attv[t];
      }
      p = wave_sum(p);
      float mn = fmaxf(m, p);
      float sc = __expf(m - mn), wgt = __expf(p - mn);
      den = den * sc + wgt;
#pragma unroll
      for (int t = 0; t < 12; t++) acc[t] = acc[t] * sc + wgt * xv[t];
      m = mn;
    }
    float inv = 1.0f / den;
    float y[12];
    float s1 = 0.f;
#pragma unroll
    for (int q = 0; q < 3; q++){
      float4 bv = *(const float4*)&bias[(lane + q * 64) * 4];
      y[q*4+0] = acc[q*4+0] * inv + bv.x;
      y[q*4+1] = acc[q*4+1] * inv + bv.y;
      y[q*4+2] = acc[q*4+2] * inv + bv.z;
      y[q*4+3] = acc[q*4+3] * inv + bv.w;
    }
#pragma unroll
    for (int t = 0; t < 12; t++) s1 += y[t];
    float mean = wave_sum(s1) * (1.0f / H);
    float s2 = 0.f;
#pragma unroll
    for (int t = 0; t < 12; t++){ float dt = y[t] - mean; s2 += dt * dt; }
    float rstd = rsqrtf(wave_sum(s2) * (1.0f / H) + 1e-5f);
    OutT* op = out + (size_t)d * H;
#pragma unroll
    for (int q = 0; q < 3; q++){
      float4 gv = *(const float4*)&g[(lane + q * 64) * 4];
      float4 bv = *(const float4*)&b[(lane + q * 64) * 4];
      float z0 = gelu_exact((y[q*4+0] - mean) * rstd * gv.x + bv.x);
      float z1 = gelu_exact((y[q*4+1] - mean) * rstd * gv.y + bv.y);
      float z2 = gelu_exact((y[q*4+2] - mean) * rstd * gv.z + bv.z);
      float z3 = gelu_exact((y[q*4+3] - mean) * rstd * gv.w + bv.w);
      if constexpr (sizeof(OutT) == 2){
        uint2 pk; pk.x = f2bf2(z0, z1); pk.y = f2bf2(z2, z3);
        *(uint2*)((unsigned*)op + lane * 2 + q * 128) = pk;
      } else {
        float4 fv; fv.x = z0; fv.y = z1; fv.z = z2; fv.w = z3;
        *(float4*)&op[(lane + q * 64) * 4] = fv;
      }
    }
  }
}

extern "C" void kernel_launch(void* const* d_in, const int* in_sizes, int n_in,
                              void* d_out, int out_size, void* d_ws, size_t ws_size,
                              hipStream_t stream){
  const float* emb   = (const float*)d_in[0];
  const float* feats = (const float*)d_in[1];
  const int*   edges = (const int*)d_in[2];
  const float* Wl2 = (const float*)d_in[4],  *bl2 = (const float*)d_in[5];
  const float* Wr2 = (const float*)d_in[6],  *br2 = (const float*)d_in[7];
  const float* att2= (const float*)d_in[8],  *bias2=(const float*)d_in[9];
  const float* Wl3 = (const float*)d_in[10], *bl3 = (const float*)d_in[11];
  const float* Wr3 = (const float*)d_in[12], *br3 = (const float*)d_in[13];
  const float* att3= (const float*)d_in[14], *bias3=(const float*)d_in[15];
  const float* g1 = (const float*)d_in[16], *b1 = (const float*)d_in[17];
  const float* g2 = (const float*)d_in[18], *b2 = (const float*)d_in[19];
  const float* g3 = (const float*)d_in[20], *b3 = (const float*)d_in[21];

  const int N  = in_sizes[1] / H;             // 50000
  const int E0 = in_sizes[2] / 2;             // 100000
  const int E  = E0 + N;                      // 150000
  const int L  = 4096;                        // labels_size
  const int Mpad = ((N + 127) / 128) * 128;            // 50048 rows capacity
  const int panels128 = Mpad / BM;                     // 391
  const int nchunk = (N + 1023) / 1024;                // 49 (<= 64)

  __hip_bfloat16* ab  = (__hip_bfloat16*)d_ws;          // [Mpad][H] GEMM input
  __hip_bfloat16* xl  = ab + (size_t)Mpad * H;          // [Mpad][H]
  __hip_bfloat16* xr  = xl + (size_t)Mpad * H;          // [Mpad][H]
  __hip_bfloat16* wt2 = xr + (size_t)Mpad * H;          // [1536][H]
  __hip_bfloat16* wt3 = wt2 + (size_t)2 * H * H;        // [1536][H]
  int* cnt   = (int*)(wt3 + (size_t)2 * H * H);         // [N]   (zeroed together:)
  int* flag  = cnt + N;                                 // [N]   S3 flags
  int* flag2 = flag + N;                                // [N]   S2 flags
  int* off   = flag2 + N;                               // [N+1]
  int* cur   = off + N + 1;                             // [N]
  int* csr   = cur + N;                                 // [E]
  int* sums  = csr + E;                                 // [64]
  int* fpos  = sums + 64;                               // [N+1] S3 scan (+count)
  int* fsums = fpos + N + 1;                            // [64]
  int* fpos2 = fsums + 64;                              // [N+1] S2 scan (+count)
  int* fsums2= fpos2 + N + 1;                           // [64]
  int* list  = fsums2 + 64;                             // [N]   S3 row list
  int* list2 = list + N;                                // [N]   S2 row list

  float* out_f = (float*)d_out;

  // output 0: passthrough copy of input_embeddings
  hipMemcpyAsync(out_f, emb, (size_t)in_sizes[0] * sizeof(float),
                 hipMemcpyDeviceToDevice, stream);

  // CSR by dst (S3-filtered) + backward-slice row sets S3 and S2
  hipMemsetAsync(cnt, 0, (size_t)3 * N * sizeof(int), stream);
  mark_s3_kernel<<<(E + 255) / 256, 256, 0, stream>>>(edges, E0, E, L, flag);
  mark2_count_kernel<<<(E + 255) / 256, 256, 0, stream>>>(edges, E0, E, flag, flag2, cnt);
  scan1_tri_kernel<<<nchunk, 1024, 0, stream>>>(cnt, off, sums, flag, fpos, fsums,
                                                flag2, fpos2, fsums2, N);
  scan2_tri_kernel<<<1, 64, 0, stream>>>(sums, off, fsums, fpos, fsums2, fpos2, nchunk, N);
  scan3_tri_kernel<<<nchunk, 1024, 0, stream>>>(off, cur, sums, fpos, fsums, flag, list,
                                                fpos2, fsums2, flag2, list2, N);
  fill_kernel<<<(E + 255) / 256, 256, 0, stream>>>(edges, E0, E, flag, cur, csr);

  // weights -> bf16 transposed, concatenated [Wl^T ; Wr^T] (one launch)
  dim3 wgrid(H / 32, H / 32, 4);
  wt_bf16_kernel<<<wgrid, 256, 0, stream>>>(Wl2, Wr2, Wl3, Wr3,
                                            wt2, wt2 + (size_t)H * H,
                                            wt3, wt3 + (size_t)H * H);

  const int* nS3 = fpos + N;    // |S3|
  const int* nS2 = fpos2 + N;   // |S2|

  // ---- layer 1 (sliced): LN over S2; xl over S2, xr over S3; aggregate dst in S3 ----
  lnw_list_kernel<<<2048, 256, 0, stream>>>(feats, g1, b1, ab, list2, nS2);
  gemm_fused_kernel<<<panels128 * 12, 256, 0, stream>>>(ab, wt2, bl2, br2, xl, xr,
                                                        list2, nS2, list, nS3, 0);
  agat_kernel<__hip_bfloat16><<<2048, 256, 0, stream>>>(
      xl, xr, att2, off, csr, edges, E0, bias2, g2, b2, ab, list, nS3, 0);

  // ---- layer 2: xl over S3; xr identity rows < L; aggregate dst < L ----
  gemm_fused_kernel<<<panels128 * 12, 256, 0, stream>>>(ab, wt3, bl3, br3, xl, xr,
                                                        list, nS3, nullptr, nullptr, L);
  agat_kernel<float><<<(L + 3) / 4, 256, 0, stream>>>(
      xl, xr, att3, off, csr, edges, E0, bias3, g3, b3, out_f + in_sizes[0],
      nullptr, nullptr, L);
}

// Round 17
// 198.019 us; speedup vs baseline: 1.5179x; 1.0140x over previous
//
#include <hip/hip_runtime.h>
#include <hip/hip_bf16.h>
#include <math.h>

#define H 768
#define BM 128

typedef __attribute__((ext_vector_type(4))) float f32x4;
typedef __attribute__((ext_vector_type(8))) short bf16x8;

__device__ __forceinline__ float bf2f(unsigned u16v){
  return __uint_as_float((u16v & 0xffffu) << 16);
}
__device__ __forceinline__ unsigned f2bf2(float a, float b){
  __hip_bfloat16 ha = __float2bfloat16(a), hb = __float2bfloat16(b);
  return (unsigned)*(unsigned short*)&ha | ((unsigned)*(unsigned short*)&hb << 16);
}
__device__ __forceinline__ float gelu_exact(float x){
  return 0.5f * x * (1.0f + erff(x * 0.70710678118654752f));
}
__device__ __forceinline__ void gload16(const void* g, void* l){
  __builtin_amdgcn_global_load_lds(
      (const __attribute__((address_space(1))) unsigned int*)g,
      (__attribute__((address_space(3))) unsigned int*)l,
      16, 0, 0);
}
__device__ __forceinline__ float wave_sum(float p){
#pragma unroll
  for (int o = 32; o; o >>= 1) p += __shfl_xor(p, o);
  return p;
}
__device__ __forceinline__ int e_src(const int* ep, int E0, int k){
  return (k < E0) ? ep[k] : (k - E0);
}
__device__ __forceinline__ int e_dst(const int* ep, int E0, int k){
  return (k < E0) ? ep[E0 + k] : (k - E0);
}

// ---------------- LayerNorm + exact GELU over a row LIST (grid-stride) ----------------
__global__ __launch_bounds__(256) void lnw_list_kernel(
    const float* __restrict__ in, const float* __restrict__ g,
    const float* __restrict__ b, __hip_bfloat16* __restrict__ out,
    const int* __restrict__ rlist, const int* __restrict__ np){
  int lim = *np;
  int lane = threadIdx.x & 63;
  for (int i = blockIdx.x * 4 + (threadIdx.x >> 6); i < lim; i += gridDim.x * 4){
    int row = rlist[i];
    const float* rp = in + (size_t)row * H;
    float v[12];
#pragma unroll
    for (int q = 0; q < 3; q++){
      float4 t = *(const float4*)&rp[(lane + q * 64) * 4];
      v[q*4+0] = t.x; v[q*4+1] = t.y; v[q*4+2] = t.z; v[q*4+3] = t.w;
    }
    float s = 0.f;
#pragma unroll
    for (int t = 0; t < 12; t++) s += v[t];
    float mean = wave_sum(s) * (1.0f / H);
    float s2 = 0.f;
#pragma unroll
    for (int t = 0; t < 12; t++){ float d = v[t] - mean; s2 += d * d; }
    float rstd = rsqrtf(wave_sum(s2) * (1.0f / H) + 1e-5f);
    unsigned* op = (unsigned*)(out + (size_t)row * H);
#pragma unroll
    for (int q = 0; q < 3; q++){
      float4 gv = *(const float4*)&g[(lane + q * 64) * 4];
      float4 bv = *(const float4*)&b[(lane + q * 64) * 4];
      float z0 = gelu_exact((v[q*4+0] - mean) * rstd * gv.x + bv.x);
      float z1 = gelu_exact((v[q*4+1] - mean) * rstd * gv.y + bv.y);
      float z2 = gelu_exact((v[q*4+2] - mean) * rstd * gv.z + bv.z);
      float z3 = gelu_exact((v[q*4+3] - mean) * rstd * gv.w + bv.w);
      uint2 pk; pk.x = f2bf2(z0, z1); pk.y = f2bf2(z2, z3);
      *(uint2*)&op[lane * 2 + q * 128] = pk;
    }
  }
}

// ---------------- weight transpose + f32->bf16 (all 4 matrices, z-indexed) ----------------
__global__ __launch_bounds__(256) void wt_bf16_kernel(
    const float* __restrict__ W0, const float* __restrict__ W1,
    const float* __restrict__ W2, const float* __restrict__ W3,
    __hip_bfloat16* __restrict__ T0, __hip_bfloat16* __restrict__ T1,
    __hip_bfloat16* __restrict__ T2, __hip_bfloat16* __restrict__ T3){
  int z = blockIdx.z;
  const float* W = (z == 0) ? W0 : (z == 1) ? W1 : (z == 2) ? W2 : W3;
  __hip_bfloat16* WT = (z == 0) ? T0 : (z == 1) ? T1 : (z == 2) ? T2 : T3;
  __shared__ float tile[32][33];
  int k0 = blockIdx.x * 32, n0 = blockIdx.y * 32;
  int tx = threadIdx.x & 31, ty = threadIdx.x >> 5;   // 32 x 8
#pragma unroll
  for (int i = 0; i < 32; i += 8)
    tile[ty + i][tx] = W[(size_t)(k0 + ty + i) * H + n0 + tx];
  __syncthreads();
#pragma unroll
  for (int i = 0; i < 32; i += 8)
    WT[(size_t)(n0 + ty + i) * H + k0 + tx] = __float2bfloat16(tile[tx][ty + i]);
}

// ---------------- 128x128 4-wave GEMM, dual row-compaction (round-14/16 validated) ----------------
__global__ __launch_bounds__(256, 3) void gemm_fused_kernel(
    const __hip_bfloat16* __restrict__ A,
    const __hip_bfloat16* __restrict__ WT,
    const float* __restrict__ bl, const float* __restrict__ br,
    __hip_bfloat16* __restrict__ Cl, __hip_bfloat16* __restrict__ Cr,
    const int* __restrict__ rmapL, const int* __restrict__ nrLp,
    const int* __restrict__ rmapR, const int* __restrict__ nrRp, int MrR){
  __shared__ char smem[49152];          // 3 x (As 8KB | Bs 8KB)

  int wgid = blockIdx.x;
  int panel = wgid / 12, colblk = wgid % 12;   // identity: spreads active blocks
  int row0 = panel * BM;
  const bool is_r = colblk >= 6;
  const int* rmap = is_r ? rmapR : rmapL;
  int nr = is_r ? (rmapR ? *nrRp : MrR) : *nrLp;
  if (row0 >= nr) return;
  const bool remap = (rmap != nullptr);

  const int t = threadIdx.x;
  const int sr = t >> 2;
  const int scs = (((t & 3) ^ ((sr >> 1) & 3)) * 8);
  const int t16 = t * 16;
  int ra0 = min(row0 + sr, nr - 1), ra1 = min(row0 + sr + 64, nr - 1);
  if (remap){ ra0 = rmap[ra0]; ra1 = rmap[ra1]; }
  const __hip_bfloat16* pa0 = A + (size_t)ra0 * H + scs;
  const __hip_bfloat16* pa1 = A + (size_t)ra1 * H + scs;
  const __hip_bfloat16* pb0 = WT + (size_t)(colblk * 128 + sr) * H + scs;
  const __hip_bfloat16* pb1 = pb0 + (size_t)64 * H;

  const int l = t & 63, w = t >> 6;
  const int wm = (w >> 1) * 64, wn = (w & 1) * 64;
  const int r0 = l & 15;
  const int kcs2 = (((l >> 4) ^ ((r0 >> 1) & 3)) * 16);

  f32x4 acc[4][4];
#pragma unroll
  for (int m = 0; m < 4; m++)
#pragma unroll
    for (int n = 0; n < 4; n++) acc[m][n] = (f32x4){0.f, 0.f, 0.f, 0.f};

#define STAGE(kt, b) do{                                   \
    int _k0 = (kt) * 32;                                   \
    char* _bs = smem + (b) * 16384;                        \
    gload16(pa0 + _k0, _bs + t16);                         \
    gload16(pa1 + _k0, _bs + 4096 + t16);                  \
    gload16(pb0 + _k0, _bs + 8192 + t16);                  \
    gload16(pb1 + _k0, _bs + 12288 + t16);                 \
  }while(0)

  STAGE(0, 0);
  STAGE(1, 1);

  for (int kt = 0; kt < 24; kt++){
    if (kt < 23) asm volatile("s_waitcnt vmcnt(4)" ::: "memory");
    else         asm volatile("s_waitcnt vmcnt(0)" ::: "memory");
    __builtin_amdgcn_s_barrier();
    __builtin_amdgcn_sched_barrier(0);
    if (kt + 2 < 24) STAGE(kt + 2, (kt + 2) % 3);
    const char* base = smem + (kt % 3) * 16384;
    bf16x8 af[4], bfr[4];
#pragma unroll
    for (int m = 0; m < 4; m++)
      af[m]  = *(const bf16x8*)(base + (wm + m * 16 + r0) * 64 + kcs2);
#pragma unroll
    for (int n = 0; n < 4; n++)
      bfr[n] = *(const bf16x8*)(base + 8192 + (wn + n * 16 + r0) * 64 + kcs2);
#pragma unroll
    for (int m = 0; m < 4; m++)
#pragma unroll
      for (int n = 0; n < 4; n++)
        acc[m][n] = __builtin_amdgcn_mfma_f32_16x16x32_bf16(af[m], bfr[n], acc[m][n], 0, 0, 0);
  }
#undef STAGE

  __syncthreads();
  const int rgrp = (l >> 4) * 4;
  const float* bp = is_r ? br : bl;
  const int cb = (is_r ? colblk - 6 : colblk) * 128;
#pragma unroll
  for (int n = 0; n < 4; n++){
    int lc = wn + n * 16 + r0;
    float bb = bp[cb + lc];
#pragma unroll
    for (int m = 0; m < 4; m++){
#pragma unroll
      for (int jj = 0; jj < 4; jj++){
        int lr = wm + m * 16 + rgrp + jj;
        int byte = lr * 256 + ((lc * 2) ^ (((lr >> 2) & 3) << 5));
        *(__hip_bfloat16*)(smem + byte) = __float2bfloat16(acc[m][n][jj] + bb);
      }
    }
  }
  __syncthreads();
  __hip_bfloat16* C = is_r ? Cr : Cl;
#pragma unroll
  for (int p = 0; p < 8; p++){
    int ba = p * 4096 + t16;
    int lr = ba >> 8, inner = ba & 255;
    int gr = row0 + lr;
    if (gr >= nr) continue;
    int orow = remap ? rmap[gr] : gr;
    uint4 v = *(const uint4*)(smem + lr * 256 + (inner ^ (((lr >> 2) & 3) << 5)));
    *(uint4*)(C + (size_t)orow * H + cb + (inner >> 1)) = v;
  }
}

// ---------------- S3 marking (srcs of dst<L edges) ----------------
__global__ __launch_bounds__(256) void mark_s3_kernel(const int* __restrict__ ep,
                                                      int E0, int E, int L,
                                                      int* __restrict__ flag){
  int k = blockIdx.x * 256 + threadIdx.x;
  if (k >= E) return;
  if (e_dst(ep, E0, k) < L) flag[e_src(ep, E0, k)] = 1;  // benign same-value race
}

// S2 marking + filtered CSR counting (only S3-dst segments are ever read back)
__global__ __launch_bounds__(256) void mark2_count_kernel(const int* __restrict__ ep,
                                                          int E0, int E,
                                                          const int* __restrict__ flag,
                                                          int* __restrict__ flag2,
                                                          int* __restrict__ cnt){
  int k = blockIdx.x * 256 + threadIdx.x;
  if (k >= E) return;
  int d = e_dst(ep, E0, k);
  if (flag[d]){
    flag2[e_src(ep, E0, k)] = 1;
    atomicAdd(&cnt[d], 1);
  }
}

// tri chunk-scan: q0 cnt->off/sums, q1 flag->fpos/fsums, q2 flag2->fpos2/fsums2
// (sums arrays hold RAW per-chunk totals; prefix computed in scan3.)
__global__ __launch_bounds__(1024) void scan1_tri_kernel(
    const int* __restrict__ a0, int* __restrict__ o0, int* __restrict__ s0,
    const int* __restrict__ a1, int* __restrict__ o1, int* __restrict__ s1,
    const int* __restrict__ a2, int* __restrict__ o2, int* __restrict__ s2, int n){
  __shared__ int lds[1024];
  const int* as[3] = {a0, a1, a2};
  int* os[3] = {o0, o1, o2};
  int* ss[3] = {s0, s1, s2};
  int tid = threadIdx.x;
  int gi = blockIdx.x * 1024 + tid;
  for (int q = 0; q < 3; q++){
    __syncthreads();
    int v = (gi < n) ? as[q][gi] : 0;
    lds[tid] = v;
    __syncthreads();
    for (int o = 1; o < 1024; o <<= 1){
      int tv = (tid >= o) ? lds[tid - o] : 0;
      __syncthreads();
      lds[tid] += tv;
      __syncthreads();
    }
    if (gi < n) os[q][gi] = lds[tid] - v;
    if (tid == 1023) ss[q][blockIdx.x] = lds[1023];
  }
}

// fused scan2+scan3: each block computes the sums-prefix locally (wave 0),
// applies offsets, inits cur, emits ordered S3/S2 lists; block 0 writes totals.
__global__ __launch_bounds__(1024) void scan3_tri_kernel(
    int* __restrict__ off, int* __restrict__ cur, const int* __restrict__ sums,
    int* __restrict__ fpos, const int* __restrict__ fsums,
    const int* __restrict__ flag, int* __restrict__ list,
    int* __restrict__ fpos2, const int* __restrict__ fsums2,
    const int* __restrict__ flag2, int* __restrict__ list2,
    int n, int nb){
  __shared__ int excl[3];               // this block's offset per array
  __shared__ int tot[3];
  int tid = threadIdx.x;
  if (tid < 64){                        // wave 0: 3 wave-scans over nb (<=64) chunks
    const int* ss[3] = {sums, fsums, fsums2};
    for (int q = 0; q < 3; q++){
      int v = (tid < nb) ? ss[q][tid] : 0;
      int incl = v;
#pragma unroll
      for (int o = 1; o < 64; o <<= 1){
        int t2 = __shfl_up(incl, o);
        if (tid >= o) incl += t2;
      }
      if (tid == (int)blockIdx.x) excl[q] = incl - v;
      if (tid == nb - 1) tot[q] = incl;
    }
  }
  __syncthreads();
  int gi = blockIdx.x * 1024 + tid;
  if (gi < n){
    int v = off[gi] + excl[0];
    off[gi] = v;
    cur[gi] = v;
    int fp = fpos[gi] + excl[1];
    fpos[gi] = fp;
    if (flag[gi]) list[fp] = gi;
    int fp2 = fpos2[gi] + excl[2];
    fpos2[gi] = fp2;
    if (flag2[gi]) list2[fp2] = gi;
  }
  if (blockIdx.x == 0 && tid < 3){      // totals: csr length, |S3|, |S2|
    if (tid == 0) off[n] = tot[0];
    if (tid == 1) fpos[n] = tot[1];
    if (tid == 2) fpos2[n] = tot[2];
  }
}

// fill CSR — only edges whose dst is aggregated (dst in S3; L ⊆ S3 via self-loops)
__global__ __launch_bounds__(256) void fill_kernel(const int* __restrict__ ep, int E0, int E,
                                                   const int* __restrict__ flag,
                                                   int* __restrict__ cur, int* __restrict__ csr){
  int k = blockIdx.x * 256 + threadIdx.x;
  if (k >= E) return;
  int d = e_dst(ep, E0, k);
  if (flag[d]) csr[atomicAdd(&cur[d], 1)] = k;
}

// ---------------- fused GAT attend+aggregate+LN+GELU: one WAVE per dst (grid-stride) ----------------
template<typename OutT>
__global__ __launch_bounds__(256) void agat_kernel(
    const __hip_bfloat16* __restrict__ xl, const __hip_bfloat16* __restrict__ xr,
    const float* __restrict__ att, const int* __restrict__ off,
    const int* __restrict__ csr, const int* __restrict__ ep, int E0,
    const float* __restrict__ bias, const float* __restrict__ g,
    const float* __restrict__ b, OutT* __restrict__ out,
    const int* __restrict__ dlist, const int* __restrict__ ndp, int ndst){
  int lim = dlist ? *ndp : ndst;
  int lane = threadIdx.x & 63;
  for (int i = blockIdx.x * 4 + (threadIdx.x >> 6); i < lim; i += gridDim.x * 4){
    int d = dlist ? dlist[i] : i;
    float xrv[12], attv[12];
    const unsigned* pr = (const unsigned*)(xr + (size_t)d * H);
#pragma unroll
    for (int q = 0; q < 3; q++){
      uint2 vr = *(const uint2*)&pr[lane * 2 + q * 128];
      float4 av = *(const float4*)&att[(lane + q * 64) * 4];
      xrv[q*4+0] = bf2f(vr.x); xrv[q*4+1] = bf2f(vr.x >> 16);
      xrv[q*4+2] = bf2f(vr.y); xrv[q*4+3] = bf2f(vr.y >> 16);
      attv[q*4+0] = av.x; attv[q*4+1] = av.y; attv[q*4+2] = av.z; attv[q*4+3] = av.w;
    }
    float m = -INFINITY, den = 0.f, acc[12];
#pragma unroll
    for (int t = 0; t < 12; t++) acc[t] = 0.f;
    int j0 = off[d], j1 = off[d + 1];
    int sj = (j0 < j1) ? e_src(ep, E0, csr[j0]) : 0;   // src prefetch pipeline
    for (int j = j0; j < j1; j++){
      int s_ = sj;
      if (j + 1 < j1) sj = e_src(ep, E0, csr[j + 1]);
      const unsigned* pl = (const unsigned*)(xl + (size_t)s_ * H);
      float xv[12];
#pragma unroll
      for (int q = 0; q < 3; q++){
        uint2 vl = *(const uint2*)&pl[lane * 2 + q * 128];
        xv[q*4+0] = bf2f(vl.x); xv[q*4+1] = bf2f(vl.x >> 16);
        xv[q*4+2] = bf2f(vl.y); xv[q*4+3] = bf2f(vl.y >> 16);
      }
      float p = 0.f;
#pragma unroll
      for (int t = 0; t < 12; t++){
        float v = xv[t] + xrv[t];
        v = (v > 0.f) ? v : 0.2f * v;
        p += v * attv[t];
      }
      p = wave_sum(p);
      float mn = fmaxf(m, p);
      float sc = __expf(m - mn), wgt = __expf(p - mn);
      den = den * sc + wgt;
#pragma unroll
      for (int t = 0; t < 12; t++) acc[t] = acc[t] * sc + wgt * xv[t];
      m = mn;
    }
    float inv = 1.0f / den;
    float y[12];
    float s1 = 0.f;
#pragma unroll
    for (int q = 0; q < 3; q++){
      float4 bv = *(const float4*)&bias[(lane + q * 64) * 4];
      y[q*4+0] = acc[q*4+0] * inv + bv.x;
      y[q*4+1] = acc[q*4+1] * inv + bv.y;
      y[q*4+2] = acc[q*4+2] * inv + bv.z;
      y[q*4+3] = acc[q*4+3] * inv + bv.w;
    }
#pragma unroll
    for (int t = 0; t < 12; t++) s1 += y[t];
    float mean = wave_sum(s1) * (1.0f / H);
    float s2 = 0.f;
#pragma unroll
    for (int t = 0; t < 12; t++){ float dt = y[t] - mean; s2 += dt * dt; }
    float rstd = rsqrtf(wave_sum(s2) * (1.0f / H) + 1e-5f);
    OutT* op = out + (size_t)d * H;
#pragma unroll
    for (int q = 0; q < 3; q++){
      float4 gv = *(const float4*)&g[(lane + q * 64) * 4];
      float4 bv = *(const float4*)&b[(lane + q * 64) * 4];
      float z0 = gelu_exact((y[q*4+0] - mean) * rstd * gv.x + bv.x);
      float z1 = gelu_exact((y[q*4+1] - mean) * rstd * gv.y + bv.y);
      float z2 = gelu_exact((y[q*4+2] - mean) * rstd * gv.z + bv.z);
      float z3 = gelu_exact((y[q*4+3] - mean) * rstd * gv.w + bv.w);
      if constexpr (sizeof(OutT) == 2){
        uint2 pk; pk.x = f2bf2(z0, z1); pk.y = f2bf2(z2, z3);
        *(uint2*)((unsigned*)op + lane * 2 + q * 128) = pk;
      } else {
        float4 fv; fv.x = z0; fv.y = z1; fv.z = z2; fv.w = z3;
        *(float4*)&op[(lane + q * 64) * 4] = fv;
      }
    }
  }
}

extern "C" void kernel_launch(void* const* d_in, const int* in_sizes, int n_in,
                              void* d_out, int out_size, void* d_ws, size_t ws_size,
                              hipStream_t stream){
  const float* emb   = (const float*)d_in[0];
  const float* feats = (const float*)d_in[1];
  const int*   edges = (const int*)d_in[2];
  const float* Wl2 = (const float*)d_in[4],  *bl2 = (const float*)d_in[5];
  const float* Wr2 = (const float*)d_in[6],  *br2 = (const float*)d_in[7];
  const float* att2= (const float*)d_in[8],  *bias2=(const float*)d_in[9];
  const float* Wl3 = (const float*)d_in[10], *bl3 = (const float*)d_in[11];
  const float* Wr3 = (const float*)d_in[12], *br3 = (const float*)d_in[13];
  const float* att3= (const float*)d_in[14], *bias3=(const float*)d_in[15];
  const float* g1 = (const float*)d_in[16], *b1 = (const float*)d_in[17];
  const float* g2 = (const float*)d_in[18], *b2 = (const float*)d_in[19];
  const float* g3 = (const float*)d_in[20], *b3 = (const float*)d_in[21];

  const int N  = in_sizes[1] / H;             // 50000
  const int E0 = in_sizes[2] / 2;             // 100000
  const int E  = E0 + N;                      // 150000
  const int L  = 4096;                        // labels_size
  const int Mpad = ((N + 127) / 128) * 128;            // 50048 rows capacity
  const int panels128 = Mpad / BM;                     // 391
  const int nchunk = (N + 1023) / 1024;                // 49 (<= 64)

  __hip_bfloat16* ab  = (__hip_bfloat16*)d_ws;          // [Mpad][H] GEMM input
  __hip_bfloat16* xl  = ab + (size_t)Mpad * H;          // [Mpad][H]
  __hip_bfloat16* xr  = xl + (size_t)Mpad * H;          // [Mpad][H]
  __hip_bfloat16* wt2 = xr + (size_t)Mpad * H;          // [1536][H]
  __hip_bfloat16* wt3 = wt2 + (size_t)2 * H * H;        // [1536][H]
  int* cnt   = (int*)(wt3 + (size_t)2 * H * H);         // [N]   (zeroed together:)
  int* flag  = cnt + N;                                 // [N]   S3 flags
  int* flag2 = flag + N;                                // [N]   S2 flags
  int* off   = flag2 + N;                               // [N+1]
  int* cur   = off + N + 1;                             // [N]
  int* csr   = cur + N;                                 // [E]
  int* sums  = csr + E;                                 // [64]
  int* fpos  = sums + 64;                               // [N+1] S3 scan (+count)
  int* fsums = fpos + N + 1;                            // [64]
  int* fpos2 = fsums + 64;                              // [N+1] S2 scan (+count)
  int* fsums2= fpos2 + N + 1;                           // [64]
  int* list  = fsums2 + 64;                             // [N]   S3 row list
  int* list2 = list + N;                                // [N]   S2 row list

  float* out_f = (float*)d_out;

  // output 0: passthrough copy of input_embeddings
  hipMemcpyAsync(out_f, emb, (size_t)in_sizes[0] * sizeof(float),
                 hipMemcpyDeviceToDevice, stream);

  // CSR by dst (S3-filtered) + backward-slice row sets S3 and S2
  hipMemsetAsync(cnt, 0, (size_t)3 * N * sizeof(int), stream);
  mark_s3_kernel<<<(E + 255) / 256, 256, 0, stream>>>(edges, E0, E, L, flag);
  mark2_count_kernel<<<(E + 255) / 256, 256, 0, stream>>>(edges, E0, E, flag, flag2, cnt);
  scan1_tri_kernel<<<nchunk, 1024, 0, stream>>>(cnt, off, sums, flag, fpos, fsums,
                                                flag2, fpos2, fsums2, N);
  scan3_tri_kernel<<<nchunk, 1024, 0, stream>>>(off, cur, sums, fpos, fsums, flag, list,
                                                fpos2, fsums2, flag2, list2, N, nchunk);
  fill_kernel<<<(E + 255) / 256, 256, 0, stream>>>(edges, E0, E, flag, cur, csr);

  // weights -> bf16 transposed, concatenated [Wl^T ; Wr^T] (one launch)
  dim3 wgrid(H / 32, H / 32, 4);
  wt_bf16_kernel<<<wgrid, 256, 0, stream>>>(Wl2, Wr2, Wl3, Wr3,
                                            wt2, wt2 + (size_t)H * H,
                                            wt3, wt3 + (size_t)H * H);

  const int* nS3 = fpos + N;    // |S3|
  const int* nS2 = fpos2 + N;   // |S2|

  // ---- layer 1 (sliced): LN over S2; xl over S2, xr over S3; aggregate dst in S3 ----
  lnw_list_kernel<<<2048, 256, 0, stream>>>(feats, g1, b1, ab, list2, nS2);
  gemm_fused_kernel<<<panels128 * 12, 256, 0, stream>>>(ab, wt2, bl2, br2, xl, xr,
                                                        list2, nS2, list, nS3, 0);
  agat_kernel<__hip_bfloat16><<<2048, 256, 0, stream>>>(
      xl, xr, att2, off, csr, edges, E0, bias2, g2, b2, ab, list, nS3, 0);

  // ---- layer 2: xl over S3; xr identity rows < L; aggregate dst < L ----
  gemm_fused_kernel<<<panels128 * 12, 256, 0, stream>>>(ab, wt3, bl3, br3, xl, xr,
                                                        list, nS3, nullptr, nullptr, L);
  agat_kernel<float><<<(L + 3) / 4, 256, 0, stream>>>(
      xl, xr, att3, off, csr, edges, E0, bias3, g3, b3, out_f + in_sizes[0],
      nullptr, nullptr, L);
}